// Round 1
// 653.094 us; speedup vs baseline: 1.0070x; 1.0070x over previous
//
#include <hip/hip_runtime.h>
#include <hip/hip_bf16.h>
#include <math.h>

#define BATCH 2
#define SEQ 4096
#define DM 1024
#define NH 16
#define DK 64
#define DV 128
#define NC 64     // number of chunks
#define CL 64     // chunk length
#define ROWS (BATCH*SEQ)   // 8192
#define DG (DM*2)          // 2048 (val/gate width)

typedef __attribute__((ext_vector_type(8))) short short8;
typedef __attribute__((ext_vector_type(4))) float floatx4;

__device__ __forceinline__ float head_decay(int h) {
    return logf(1.0f - exp2f(-5.0f - (float)h));
}
__device__ __forceinline__ unsigned short bfbits(float v) {
    __hip_bfloat16 h = __float2bfloat16(v);
    return *(unsigned short*)&h;
}
__device__ __forceinline__ float bf2f(unsigned short u) {
    unsigned x = ((unsigned)u) << 16;
    return *(float*)&x;
}
__device__ __forceinline__ unsigned pack2(float a, float b) {
    return (unsigned)bfbits(a) | ((unsigned)bfbits(b) << 16);
}
__device__ __forceinline__ void unpack8(uint4 u, float* dst) {
    dst[0]=bf2f((unsigned short)(u.x&0xffff)); dst[1]=bf2f((unsigned short)(u.x>>16));
    dst[2]=bf2f((unsigned short)(u.y&0xffff)); dst[3]=bf2f((unsigned short)(u.y>>16));
    dst[4]=bf2f((unsigned short)(u.z&0xffff)); dst[5]=bf2f((unsigned short)(u.z>>16));
    dst[6]=bf2f((unsigned short)(u.w&0xffff)); dst[7]=bf2f((unsigned short)(u.w>>16));
}
__device__ __forceinline__ void gld_lds16(const unsigned short* g, unsigned short* l) {
    __builtin_amdgcn_global_load_lds(
        (const __attribute__((address_space(1))) unsigned int*)g,
        (__attribute__((address_space(3))) unsigned int*)l, 16, 0, 0);
}

// barrier WITHOUT the vmcnt(0) drain that __syncthreads() inserts
#define BAR() do { asm volatile("" ::: "memory"); \
    __builtin_amdgcn_s_barrier(); \
    asm volatile("" ::: "memory"); } while(0)
#define BAR_LG() do { asm volatile("" ::: "memory"); \
    __builtin_amdgcn_s_barrier(); \
    asm volatile("s_waitcnt lgkmcnt(0)" ::: "memory"); } while(0)

// ---------------- LN + cast to bf16: one block per row ----------------
__global__ __launch_bounds__(256) void ln_cvt_kernel(const float* __restrict__ x,
        const float* __restrict__ g, const float* __restrict__ b,
        unsigned short* __restrict__ xbf) {
    int row = blockIdx.x;
    const float* xr = x + (size_t)row * DM;
    int c0 = threadIdx.x * 4;
    float4 v = *(const float4*)&xr[c0];
    float s1 = v.x + v.y + v.z + v.w;
    float s2 = v.x*v.x + v.y*v.y + v.z*v.z + v.w*v.w;
#pragma unroll
    for (int off = 32; off > 0; off >>= 1) {
        s1 += __shfl_down(s1, off);
        s2 += __shfl_down(s2, off);
    }
    __shared__ float a1[4], a2[4];
    int wid = threadIdx.x >> 6;
    if ((threadIdx.x & 63) == 0) { a1[wid] = s1; a2[wid] = s2; }
    __syncthreads();
    s1 = a1[0] + a1[1] + a1[2] + a1[3];
    s2 = a2[0] + a2[1] + a2[2] + a2[3];
    float mu = s1 * (1.f/DM);
    float var = s2 * (1.f/DM) - mu*mu;
    float rstd = rsqrtf(var + 1e-5f);
    float o0 = (v.x - mu)*rstd*g[c0+0] + b[c0+0];
    float o1 = (v.y - mu)*rstd*g[c0+1] + b[c0+1];
    float o2 = (v.z - mu)*rstd*g[c0+2] + b[c0+2];
    float o3 = (v.w - mu)*rstd*g[c0+3] + b[c0+3];
    uint2 p; p.x = pack2(o0, o1); p.y = pack2(o2, o3);
    *(uint2*)&xbf[(size_t)row*DM + c0] = p;
}

// ---------------- fp32 -> bf16 weight conversion ----------------
__global__ __launch_bounds__(256) void cvt_bf16_kernel(const float* __restrict__ src,
        unsigned short* __restrict__ dst, int n4) {
    int i = blockIdx.x * 256 + threadIdx.x;
    if (i < n4) {
        float4 v = ((const float4*)src)[i];
        uint2 p; p.x = pack2(v.x, v.y); p.y = pack2(v.z, v.w);
        ((uint2*)dst)[i] = p;
    }
}

// ============ QKVG GEMM: 256x256 tile, BK=64, 8-wave, 8-phase counted-vmcnt ============
// A(8192x1024,bf16) x Wcat(6144x1024,bf16)^T. 768 blocks of 512 threads, 128 KiB LDS.
// Buffers (shorts): Ab0=[0], Ab1=[16384], Bb0=[32768], Bb1=[49152]; each 256x64,
// 16B-block XOR swizzle: LDS block bl of row r holds global k-block bl^(r&7).
// Iteration i computes K-tiles 2i (buf0, P1-P4) and 2i+1 (buf1, P5-P8); per wave
// 128x64 output = acc[8][4], 16 MFMA/phase. Half-tile stage schedule (race-free:
// each stage is issued >=1 barrier after the target region's last ds_read, and
// vmcnt(4)+barrier at P4/P8 guarantees landing before first consume; vmcnt is
// NEVER 0 in the loop):
//   P1: B(2i+1)h0->Bb1   P2: B(2i+1)h1   P3: B(2i+2)h0->Bb0  P4: B(2i+2)h1, vmcnt(4)
//   P5: A(2i+2)h0->Ab0   P6: A(2i+2)h1   P7: --              P8: A(2i+3)h0+h1->Ab1, vmcnt(4)
// Reads: P1/P5: A[m0-3]+B[n0-1] (12xb128); P2/P6: B[n2-3]; P3/P7: A[m4-7]; P4/P8: none.
// Last iteration stages tiles >=nkt: lands in buffers after their final reads and
// is never consumed; addresses overrun K by <=1152 shorts into adjacent ws regions (safe).
// Epilogue reuses smem[0:16384] ([64][256] bf16) only -- disjoint from the still-
// outstanding tail stage (targets Ab1).
__global__ __launch_bounds__(512, 2) void gemm_qkvg_8ph(
        const unsigned short* __restrict__ A, const unsigned short* __restrict__ W,
        const float* __restrict__ b0, const float* __restrict__ b1,
        const float* __restrict__ b2, const float* __restrict__ b3,
        unsigned short* __restrict__ o0, unsigned short* __restrict__ o1,
        unsigned short* __restrict__ o2, unsigned short* __restrict__ o3) {
    constexpr int KK  = DM;         // 1024
    constexpr int NIT = KK / 128;   // 8 iterations x 2 K-tiles
    constexpr int AB0 = 0, AB1 = 16384, BB0 = 32768, BB1 = 49152;
    __shared__ __align__(16) unsigned short smem[65536];   // 128 KiB

    // XCD-contiguous raster (768 % 8 == 0 -> simple swizzle is bijective),
    // then 4 bm x 24 bn groups per XCD for L2 reuse.
    const int nbn = 6144 >> 8;                 // 24
    const int nb  = (ROWS >> 8) * nbn;         // 768
    const int per = nb >> 3;                   // 96
    int id = blockIdx.x;
    int logical = (id & 7) * per + (id >> 3);
    const int in_grp = 4 * nbn;                // 96
    int g   = logical / in_grp;
    int rem = logical - g * in_grp;
    const int bm = (g * 4 + (rem & 3)) << 8;
    const int bn = (rem >> 2) << 8;

    const int tid  = threadIdx.x;
    const int lane = tid & 63;
    const int wave = tid >> 6;
    const int warp_m = wave >> 2, warp_n = wave & 3;   // 2 x 4 wave grid
    const int fm = lane & 15, kq = lane >> 4;

    // staging map: row = tid>>3 (64 rows/round), 16B block (tid&7) holds global
    // block (tid&7)^(row&7); global_load_lds dest = linear base + tid*16B.
    const int srow = tid >> 3;
    const int scol = ((tid & 7) ^ (srow & 7)) * 8;
    const unsigned short* Asrc = A + (size_t)(bm + srow) * KK + scol;
    const unsigned short* Wsrc = W + (size_t)(bn + srow) * KK + scol;

    int kcol[2];
#pragma unroll
    for (int ks = 0; ks < 2; ks++) kcol[ks] = ((ks*4 + kq) ^ (fm & 7)) * 8;
    const int afm = warp_m * 8192 + fm * 64;
    const int bfm = warp_n * 4096 + fm * 64;

    floatx4 acc[8][4] = {};
    short8 aF[8], bF[8];

    auto stageHalf = [&](int ldsoff, const unsigned short* gsrc) {
        gld_lds16(gsrc,          &smem[ldsoff + tid*8]);
        gld_lds16(gsrc + 64*KK,  &smem[ldsoff + 4096 + tid*8]);
    };
    auto rdA = [&](int buf, int mi0) {
#pragma unroll
        for (int mi = 0; mi < 4; mi++)
#pragma unroll
            for (int ks = 0; ks < 2; ks++)
                aF[mi*2+ks] = *(const short8*)&smem[buf + afm + (mi0+mi)*1024 + kcol[ks]];
    };
    auto rdB = [&](int buf, int ni0) {
#pragma unroll
        for (int ni = 0; ni < 2; ni++)
#pragma unroll
            for (int ks = 0; ks < 2; ks++)
                bF[(ni0+ni)*2+ks] = *(const short8*)&smem[buf + bfm + (ni0+ni)*1024 + kcol[ks]];
    };
    auto mma = [&](int mi0, int ni0) {
        __builtin_amdgcn_s_setprio(1);
#pragma unroll
        for (int mi = 0; mi < 4; mi++)
#pragma unroll
            for (int ni = 0; ni < 2; ni++)
#pragma unroll
                for (int ks = 0; ks < 2; ks++)
                    acc[mi0+mi][ni0+ni] = __builtin_amdgcn_mfma_f32_16x16x32_bf16(
                        aF[mi*2+ks], bF[(ni0+ni)*2+ks], acc[mi0+mi][ni0+ni], 0, 0, 0);
        __builtin_amdgcn_s_setprio(0);
    };

    // ---- prologue: A(0),B(0) -> buf0 (8 loads); A(1) -> Ab1 (4 loads) ----
    stageHalf(AB0,        Asrc);
    stageHalf(AB0 + 8192, Asrc + 128*KK);
    stageHalf(BB0,        Wsrc);
    stageHalf(BB0 + 8192, Wsrc + 128*KK);
    stageHalf(AB1,        Asrc + 64);
    stageHalf(AB1 + 8192, Asrc + 128*KK + 64);
    asm volatile("s_waitcnt vmcnt(4)" ::: "memory");   // A0,B0 landed; A1 in flight
    BAR();

#pragma unroll 1
    for (int i = 0; i < NIT; i++) {
        const int kB1 = (2*i + 1) * 64;
        const int kN  = (2*i + 2) * 64;
        // ---- P1 (tile 2i, buf0) ----
        rdA(AB0, 0); rdB(BB0, 0);
        stageHalf(BB1, Wsrc + kB1);
        BAR_LG();
        mma(0, 0);
        BAR();
        // ---- P2 ----
        rdB(BB0, 2);
        stageHalf(BB1 + 8192, Wsrc + 128*KK + kB1);
        BAR_LG();
        mma(0, 2);
        BAR();
        // ---- P3 ----
        rdA(AB0, 4);
        stageHalf(BB0, Wsrc + kN);
        BAR_LG();
        mma(4, 0);
        BAR();
        // ---- P4 ----
        stageHalf(BB0 + 8192, Wsrc + 128*KK + kN);
        BAR_LG();
        mma(4, 2);
        asm volatile("s_waitcnt vmcnt(4)" ::: "memory"); // A(2i+1),B(2i+1) landed
        BAR();
        // ---- P5 (tile 2i+1, buf1) ----
        rdA(AB1, 0); rdB(BB1, 0);
        stageHalf(AB0, Asrc + kN);
        BAR_LG();
        mma(0, 0);
        BAR();
        // ---- P6 ----
        rdB(BB1, 2);
        stageHalf(AB0 + 8192, Asrc + 128*KK + kN);
        BAR_LG();
        mma(0, 2);
        BAR();
        // ---- P7 ----
        rdA(AB1, 4);
        BAR_LG();
        mma(4, 0);
        BAR();
        // ---- P8 ----
        stageHalf(AB1,        Asrc + kN + 64);
        stageHalf(AB1 + 8192, Asrc + 128*KK + kN + 64);
        BAR_LG();
        mma(4, 2);
        asm volatile("s_waitcnt vmcnt(4)" ::: "memory"); // A(2i+2),B(2i+2) landed
        BAR();
    }

    // ---- segment routing + epilogue through smem[0:16384] ([64][256] bf16) ----
    int seg = bn >> 10;
    unsigned short* obf; const float* bias; int No, lcb; bool doRope = false; float scale = 1.f;
    if (seg == 0)      { obf = o0; bias = b0; No = 1024; lcb = bn;        doRope = true; }
    else if (seg == 1) { obf = o1; bias = b1; No = 1024; lcb = bn - 1024; doRope = true; scale = 0.125f; }
    else if (seg <= 3) { obf = o2; bias = b2; No = 2048; lcb = bn - 2048; }
    else               { obf = o3; bias = b3; No = 2048; lcb = bn - 4096; }

    const int crow = (lane >> 4) * 4, ccol = lane & 15;
    for (int pass = 0; pass < 4; pass++) {
        if (warp_m == (pass >> 1)) {              // wave-uniform
            int mi0 = (pass & 1) * 4;
#pragma unroll
            for (int mi = 0; mi < 4; mi++) {
#pragma unroll
                for (int ni = 0; ni < 4; ni++) {
                    int tcol = warp_n*64 + ni*16 + ccol;
                    float bcol = bias[lcb + tcol];
#pragma unroll
                    for (int r = 0; r < 4; r++) {
                        int gr = warp_m*128 + (mi0+mi)*16 + crow + r;
                        float v = (acc[mi0+mi][ni][r] + bcol) * scale;
                        if (doRope) {
                            float vp = __shfl_xor(v, 1);   // partner col (tcol^1)
                            int s = (bm + gr) & (SEQ-1);
                            int jj = (tcol & 63) >> 1;
                            float ang = exp2f(-(float)jj * (13.287712379549449f/31.f));
                            float sn, cs;
                            sincosf((float)s * ang, &sn, &cs);
                            v = (tcol & 1) ? (v*cs + vp*sn) : (v*cs - vp*sn);
                        }
                        smem[(gr & 63)*256 + tcol] = bfbits(v);
                    }
                }
            }
        }
        __syncthreads();
        {   // 64 rows x 512B; 512 thr x 16B = 16 rows/round, 4 rounds
            int rrow = tid >> 5, rc = (tid & 31) * 8;
#pragma unroll
            for (int it = 0; it < 4; it++) {
                int lr = it*16 + rrow;
                uint4 u = *(const uint4*)&smem[lr*256 + rc];
                *(uint4*)&obf[(size_t)(bm + pass*64 + lr)*No + lcb + rc] = u;
            }
        }
        __syncthreads();
    }
}

// ---------------- bf16 MFMA NT GEMM, 128x128 tile, BK=64, XOR-swizzled LDS ----------------
// (retained for the Wo GEMM; QKVG path moved to gemm_qkvg_8ph above)
template<bool QKVG>
__global__ __launch_bounds__(256) void gemm_mfma(
        const unsigned short* __restrict__ A, const unsigned short* __restrict__ W,
        int K, int Ntot,
        const float* __restrict__ b0, const float* __restrict__ b1,
        const float* __restrict__ b2, const float* __restrict__ b3,
        void* __restrict__ o0, void* __restrict__ o1,
        void* __restrict__ o2, void* __restrict__ o3) {
    const int nbn = Ntot >> 7;
    const int nb  = (ROWS >> 7) * nbn;
    const int per = nb >> 3;
    int id = blockIdx.x;
    int logical = (id & 7) * per + (id >> 3);
    const int in_grp = 8 * nbn;
    int g   = logical / in_grp;
    int rem = logical - g * in_grp;
    const int bm = (g * 8 + (rem & 7)) << 7;
    const int bn = (rem >> 3) << 7;

    __shared__ unsigned short smem[16384];     // 32 KB: As[128][64] | Bs[128][64]; epi aliases
    unsigned short* As = smem;
    unsigned short* Bs = smem + 8192;

    const int tid = threadIdx.x;
    const int wave = tid >> 6, lane = tid & 63;
    const int wm = (wave & 1) * 64, wn = (wave >> 1) * 64;

    const int sr = tid >> 3;
    const int scol = (((tid & 7) ^ (sr & 7)) * 8);
    const unsigned short* Ag = A + (size_t)(bm + sr) * K + scol;
    const unsigned short* Wg = W + (size_t)(bn + sr) * K + scol;
    const int fm = lane & 15;
    const int kq = lane >> 4;

    floatx4 acc[4][4] = {};
    for (int k0 = 0; k0 < K; k0 += 64) {
#pragma unroll
        for (int t = 0; t < 4; t++) {
            gld_lds16(Ag + (size_t)(t*32)*K + k0, &As[t*2048 + tid*8]);
            gld_lds16(Wg + (size_t)(t*32)*K + k0, &Bs[t*2048 + tid*8]);
        }
        __syncthreads();
#pragma unroll
        for (int half = 0; half < 2; half++) {
            const int kb = half*4 + kq;
            short8 af[4], bfv[4];
#pragma unroll
            for (int mi = 0; mi < 4; mi++) {
                int r = wm + mi*16 + fm;
                af[mi] = *(const short8*)&As[r*64 + ((kb ^ (r & 7))*8)];
            }
#pragma unroll
            for (int ni = 0; ni < 4; ni++) {
                int r = wn + ni*16 + fm;
                bfv[ni] = *(const short8*)&Bs[r*64 + ((kb ^ (r & 7))*8)];
            }
#pragma unroll
            for (int mi = 0; mi < 4; mi++)
#pragma unroll
                for (int ni = 0; ni < 4; ni++)
                    acc[mi][ni] = __builtin_amdgcn_mfma_f32_16x16x32_bf16(
                                      af[mi], bfv[ni], acc[mi][ni], 0, 0, 0);
        }
        __syncthreads();
    }

    float scale = 1.f; bool doRope = false;
    const float* bias; int No, lcb;
    unsigned short* obf = nullptr; float* of32 = nullptr;
    if (QKVG) {
        int seg = bn >> 10;
        if (seg == 0)      { obf = (unsigned short*)o0; bias = b0; No = 1024; lcb = bn;        doRope = true; }
        else if (seg == 1) { obf = (unsigned short*)o1; bias = b1; No = 1024; lcb = bn - 1024; doRope = true; scale = 0.125f; }
        else if (seg <= 3) { obf = (unsigned short*)o2; bias = b2; No = 2048; lcb = bn - 2048; }
        else               { obf = (unsigned short*)o3; bias = b3; No = 2048; lcb = bn - 4096; }
    } else {
        of32 = (float*)o0; bias = b0; No = Ntot; lcb = bn;
    }

    const int crow = (lane >> 4) * 4, ccol = lane & 15;
    unsigned short* epib = smem;
    float* epif = (float*)smem;
    for (int pass = 0; pass < 2; pass++) {
#pragma unroll
        for (int mi = 0; mi < 4; mi++) {
            if (((wm + mi*16) >> 6) != pass) continue;
#pragma unroll
            for (int ni = 0; ni < 4; ni++) {
                int tcol = wn + ni*16 + ccol;
                float bcol = bias[lcb + tcol];
#pragma unroll
                for (int r = 0; r < 4; r++) {
                    int gr = wm + mi*16 + crow + r;
                    float v = (acc[mi][ni][r] + bcol) * scale;
                    if (QKVG) {
                        if (doRope) {
                            float vp = __shfl_xor(v, 1);
                            int s = (bm + gr) & (SEQ-1);
                            int jj = (tcol & 63) >> 1;
                            float ang = exp2f(-(float)jj * (13.287712379549449f/31.f));
                            float sn, cs;
                            sincosf((float)s * ang, &sn, &cs);
                            v = (tcol & 1) ? (v*cs + vp*sn) : (v*cs - vp*sn);
                        }
                        epib[(gr & 63)*128 + tcol] = bfbits(v);
                    } else {
                        epif[(gr & 63)*128 + tcol] = v;
                    }
                }
            }
        }
        __syncthreads();
        if (QKVG) {
            int rrow = tid >> 4, rc = (tid & 15) * 8;
#pragma unroll
            for (int it = 0; it < 4; it++) {
                int lr = it*16 + rrow;
                uint4 u = *(const uint4*)&epib[lr*128 + rc];
                *(uint4*)&obf[(size_t)(bm + pass*64 + lr)*No + lcb + rc] = u;
            }
        } else {
            int rrow = tid >> 5, rc = (tid & 31) * 4;
#pragma unroll
            for (int it = 0; it < 8; it++) {
                int lr = it*8 + rrow;
                uint4 u = *(const uint4*)&epif[lr*128 + rc];
                *(uint4*)&of32[(size_t)(bm + pass*64 + lr)*No + lcb + rc] = u;
            }
        }
        __syncthreads();
    }
}

// ---------------- retention per-chunk (bf16 in, inner_out in-place bf16, KV fp32) ----------------
__global__ __launch_bounds__(256) void ret_inner_kernel(
        const unsigned short* __restrict__ qry, const unsigned short* __restrict__ key,
        unsigned short* __restrict__ valio, float* __restrict__ kv_out,
        float* __restrict__ iscale_out) {
    int blk = blockIdx.x;
    int c = blk & 63;
    int h = (blk >> 6) & 15;
    int b = blk >> 10;
    float dec = head_decay(h);

    __shared__ float uni[64*65];
    __shared__ float Ks[CL][DK+1];
    __shared__ float Ss[CL][CL+1];
    __shared__ float ascale[CL];
    __shared__ float iscale[CL];

    int tid = threadIdx.x;
    size_t qkbase = ((size_t)(b*SEQ + c*CL))*DM + (size_t)h*DK;
#pragma unroll
    for (int it = 0; it < 2; it++) {
        int s = tid + it*256;
        int i = s >> 3, c0 = (s & 7)*8;
        uint4 uq = *(const uint4*)&qry[qkbase + (size_t)i*DM + c0];
        uint4 uk = *(const uint4*)&key[qkbase + (size_t)i*DM + c0];
        unpack8(uq, &uni[i*65 + c0]);
        unpack8(uk, &Ks[i][c0]);
    }
    if (tid < CL) {
        float ssum = 0.f;
        for (int t = 0; t <= tid; t++) ssum += expf(dec * (float)t);
        ascale[tid] = sqrtf(ssum);
    }
    __syncthreads();

    {
        int tx = tid & 15, ty = tid >> 4;
        float acc[4][4] = {};
        for (int d = 0; d < DK; d++) {
            float av[4], bv[4];
#pragma unroll
            for (int i = 0; i < 4; i++) av[i] = uni[(ty*4+i)*65 + d];
#pragma unroll
            for (int j = 0; j < 4; j++) bv[j] = Ks[tx*4+j][d];
#pragma unroll
            for (int i = 0; i < 4; i++)
#pragma unroll
                for (int j = 0; j < 4; j++)
                    acc[i][j] += av[i]*bv[j];
        }
#pragma unroll
        for (int i = 0; i < 4; i++) {
            int ri = ty*4 + i;
            float ra = 1.f / ascale[ri];
#pragma unroll
            for (int j = 0; j < 4; j++) {
                int cj = tx*4 + j;
                float m = (cj <= ri) ? expf(dec*(float)(ri-cj)) * ra : 0.f;
                Ss[ri][cj] = acc[i][j] * m;
            }
        }
    }
    __syncthreads();
    if (tid < CL) {
        float rs = 0.f;
        for (int j = 0; j < CL; j++) rs += Ss[tid][j];
        float isc = fmaxf(fabsf(rs), 1.f);
        iscale[tid] = isc;
        iscale_out[(size_t)blk*CL + tid] = isc;
    }

    int txv = tid & 15, tyv = tid >> 4;
    int v0 = txv*4, i0 = tyv*4;
    size_t vbase = ((size_t)(b*SEQ + c*CL))*DG + (size_t)h*DV;
    for (int half = 0; half < 2; half++) {
        __syncthreads();
#pragma unroll
        for (int it = 0; it < 2; it++) {
            int s = tid + it*256;
            int i = s >> 3, c0 = (s & 7)*8;
            uint4 uv = *(const uint4*)&valio[vbase + (size_t)i*DG + half*64 + c0];
            unpack8(uv, &uni[i*64 + c0]);
        }
        __syncthreads();
        float acc2[4][4] = {};
        float acc3[4][4] = {};
        for (int j = 0; j < CL; j++) {
            float4 vv = *(const float4*)&uni[j*64 + v0];
            float va[4] = {vv.x, vv.y, vv.z, vv.w};
#pragma unroll
            for (int r = 0; r < 4; r++) {
                float s  = Ss[i0+r][j];
                float kk = Ks[j][i0+r];
#pragma unroll
                for (int q = 0; q < 4; q++) {
                    acc2[r][q] += s*va[q];
                    acc3[r][q] += kk*va[q];
                }
            }
        }
#pragma unroll
        for (int r = 0; r < 4; r++) {
            int i = i0 + r;
            float inv = 1.f / iscale[i];
            uint2 p;
            p.x = pack2(acc2[r][0]*inv, acc2[r][1]*inv);
            p.y = pack2(acc2[r][2]*inv, acc2[r][3]*inv);
            *(uint2*)&valio[vbase + (size_t)i*DG + half*64 + v0] = p;
            float4 kvo = make_float4(acc3[r][0], acc3[r][1], acc3[r][2], acc3[r][3]);
            *(float4*)&kv_out[(size_t)blk*(DK*DV) + (size_t)i*DV + half*64 + v0] = kvo;
        }
    }
}

// ---------------- sequential scan over chunks (in-place KV -> cross_chunk) ----------------
__global__ __launch_bounds__(256) void ret_scan_kernel(float* __restrict__ kv,
        float* __restrict__ cscale_out) {
    int tid = threadIdx.x;
    int col = blockIdx.x*16 + ((tid >> 6) << 2) + (tid & 3);
    int kp  = (tid >> 2) & 15;
    int v   = col & 127;
    int bh  = col >> 7;
    int h   = bh & 15;
    float dec = head_decay(h);
    float cdecay = expf(dec * (float)CL);
    float state[4] = {0.f, 0.f, 0.f, 0.f};
    float scale = 1.f;
    size_t base0 = (size_t)bh*NC*(DK*DV) + (size_t)(kp*4)*DV + v;
    float cur[4];
#pragma unroll
    for (int kk = 0; kk < 4; kk++) cur[kk] = kv[base0 + (size_t)kk*DV];
    for (int c = 0; c < NC; c++) {
        size_t base = base0 + (size_t)c*(DK*DV);
        float nxt[4];
        if (c+1 < NC) {
            size_t nb = base + (size_t)(DK*DV);
#pragma unroll
            for (int kk = 0; kk < 4; kk++) nxt[kk] = kv[nb + (size_t)kk*DV];
        }
        float inv = 1.f / scale;
#pragma unroll
        for (int kk = 0; kk < 4; kk++) kv[base + (size_t)kk*DV] = cur[kk]*inv;
        if (kp == 0) cscale_out[((size_t)bh*NC + c)*DV + v] = scale;
        float ssum = 0.f;
#pragma unroll
        for (int kk = 0; kk < 4; kk++) {
            state[kk] = state[kk]*cdecay + cur[kk];
            ssum += fabsf(state[kk]);
        }
        ssum += __shfl_xor(ssum, 4);
        ssum += __shfl_xor(ssum, 8);
        ssum += __shfl_xor(ssum, 16);
        ssum += __shfl_xor(ssum, 32);
        scale = fmaxf(ssum, 1.f);
        if (c+1 < NC) {
#pragma unroll
            for (int kk = 0; kk < 4; kk++) cur[kk] = nxt[kk];
        }
    }
}

// ---------------- cross_out + combine + groupnorm + silu(gate), in-place bf16 ----------------
__global__ __launch_bounds__(256) void ret_cross_kernel(
        const unsigned short* __restrict__ qry, const float* __restrict__ cross_chunk,
        unsigned short* __restrict__ valio, const float* __restrict__ iscale,
        const float* __restrict__ cscale, const unsigned short* __restrict__ gatebf,
        const float* __restrict__ gn_g, const float* __restrict__ gn_b) {
    int blk = blockIdx.x;
    int c = blk & 63, h = (blk >> 6) & 15, b = blk >> 10;
    float dec = head_decay(h);
    __shared__ float Qs[CL][DK+1];
    __shared__ float CC[DK][DV];
    __shared__ float asc[CL];
    __shared__ float idec[CL];

    int tid = threadIdx.x;
    size_t qbase = ((size_t)(b*SEQ + c*CL))*DM + (size_t)h*DK;
#pragma unroll
    for (int it = 0; it < 2; it++) {
        int s = tid + it*256;
        int i = s >> 3, c0 = (s & 7)*8;
        uint4 uq = *(const uint4*)&qry[qbase + (size_t)i*DM + c0];
        unpack8(uq, &Qs[i][c0]);
    }
    size_t cbase = (size_t)blk * (DK*DV);
#pragma unroll
    for (int t = 0; t < 32; t++) {
        int idx = tid + t*256;
        CC[idx >> 7][idx & 127] = cross_chunk[cbase + idx];
    }
    if (tid < CL) {
        float ssum = 0.f;
        for (int t = 0; t <= tid; t++) ssum += expf(dec * (float)t);
        asc[tid] = sqrtf(ssum);
    }
    __syncthreads();
    if (tid < CL) idec[tid] = expf(dec*(float)(tid+1)) * asc[CL-1] / asc[tid];
    __syncthreads();

    int txv = tid & 31, tyv = tid >> 5;
    int v0 = txv*4, i0 = tyv*8;
    float acc[8][4] = {};
    for (int k = 0; k < DK; k++) {
        float4 cv = *(const float4*)&CC[k][v0];
        float ca[4] = {cv.x, cv.y, cv.z, cv.w};
#pragma unroll
        for (int r = 0; r < 8; r++) {
            float qv = Qs[i0+r][k];
#pragma unroll
            for (int q = 0; q < 4; q++) acc[r][q] += qv*ca[q];
        }
    }
    float4 csv = *(const float4*)&cscale[(size_t)blk*DV + v0];
    float csa[4] = {csv.x, csv.y, csv.z, csv.w};
    float o[8][4];
    float s1[8], s2[8];
#pragma unroll
    for (int r = 0; r < 8; r++) {
        int i = i0 + r;
        float f2 = idec[i] / iscale[(size_t)blk*CL + i];
        size_t orow = ((size_t)(b*SEQ + c*CL + i))*DG + (size_t)h*DV + v0;
        uint2 iu = *(const uint2*)&valio[orow];
        float ioa[4] = { bf2f((unsigned short)(iu.x & 0xffff)),
                         bf2f((unsigned short)(iu.x >> 16)),
                         bf2f((unsigned short)(iu.y & 0xffff)),
                         bf2f((unsigned short)(iu.y >> 16)) };
        float rs1 = 0.f, rs2 = 0.f;
#pragma unroll
        for (int q = 0; q < 4; q++) {
            float ov = ioa[q]/csa[q] + acc[r][q]*f2;
            o[r][q] = ov;
            rs1 += ov; rs2 += ov*ov;
        }
        s1[r] = rs1; s2[r] = rs2;
    }
#pragma unroll
    for (int r = 0; r < 8; r++) {
#pragma unroll
        for (int m = 1; m <= 16; m <<= 1) {
            s1[r] += __shfl_xor(s1[r], m);
            s2[r] += __shfl_xor(s2[r], m);
        }
    }
#pragma unroll
    for (int r = 0; r < 8; r++) {
        int i = i0 + r;
        float mu = s1[r] * (1.f/DV);
        float var = s2[r] * (1.f/DV) - mu*mu;
        float rstd = rsqrtf(var + 1e-5f);
        size_t orow = ((size_t)(b*SEQ + c*CL + i))*DG + (size_t)h*DV + v0;
        uint2 gu = *(const uint2*)&gatebf[orow];
        float ga[4] = { bf2f((unsigned short)(gu.x & 0xffff)),
                        bf2f((unsigned short)(gu.x >> 16)),
                        bf2f((unsigned short)(gu.y & 0xffff)),
                        bf2f((unsigned short)(gu.y >> 16)) };
        float res[4];
#pragma unroll
        for (int q = 0; q < 4; q++) {
            int col = h*DV + v0 + q;
            float xn = (o[r][q] - mu)*rstd*gn_g[col] + gn_b[col];
            float sg = ga[q] / (1.f + expf(-ga[q]));
            res[q] = xn * sg;
        }
        uint2 p; p.x = pack2(res[0], res[1]); p.y = pack2(res[2], res[3]);
        *(uint2*)&valio[orow] = p;
    }
}

extern "C" void kernel_launch(void* const* d_in, const int* in_sizes, int n_in,
                              void* d_out, int out_size, void* d_ws, size_t ws_size,
                              hipStream_t stream) {
    (void)in_sizes; (void)n_in; (void)out_size; (void)ws_size;
    const float* x    = (const float*)d_in[0];
    const float* W_q  = (const float*)d_in[2];
    const float* b_q  = (const float*)d_in[3];
    const float* W_k  = (const float*)d_in[4];
    const float* b_k  = (const float*)d_in[5];
    const float* W_v  = (const float*)d_in[6];
    const float* b_v  = (const float*)d_in[7];
    const float* W_g  = (const float*)d_in[8];
    const float* b_g  = (const float*)d_in[9];
    const float* W_o  = (const float*)d_in[10];
    const float* b_o  = (const float*)d_in[11];
    const float* ln_g = (const float*)d_in[12];
    const float* ln_b = (const float*)d_in[13];
    const float* gn_g = (const float*)d_in[14];
    const float* gn_b = (const float*)d_in[15];
    float* out = (float*)d_out;
    float* ws  = (float*)d_ws;

    // workspace layout (floats) — total ~39.2M floats = 157 MB
    float* keyb   = ws;                       //  4,194,304 (bf16 key 8192x1024)
    float* valb   = keyb   + 4194304;         //  8,388,608 (bf16 val->inner_out->acts 8192x2048)
    float* gateb  = valb   + 8388608;         //  8,388,608 (bf16 gate)
    float* kvbuf  = gateb  + 8388608;         // 16,777,216 fp32 KV->cross_chunk
    float* iscale = kvbuf  + 16777216;        //    131,072
    float* cscale = iscale + 131072;          //    262,144
    float* wobuf  = cscale + 262144;          //  1,048,576 (bf16 W_o 1024x2048)

    unsigned short* xbf  = (unsigned short*)kvbuf;             // 8,388,608 bf16
    unsigned short* Wcat = (unsigned short*)(kvbuf + 4194304); // 6,291,456 bf16 (6144x1024)
    unsigned short* Wo_bf  = (unsigned short*)wobuf;
    unsigned short* key_bf = (unsigned short*)keyb;
    unsigned short* val_bf = (unsigned short*)valb;
    unsigned short* gate_bf= (unsigned short*)gateb;
    unsigned short* qry_bf = (unsigned short*)out;   // d_out doubles as bf16 qry scratch

    ln_cvt_kernel<<<ROWS, 256, 0, stream>>>(x, ln_g, ln_b, xbf);
    cvt_bf16_kernel<<<(DM*DM/4 + 255)/256, 256, 0, stream>>>(W_q, Wcat,             DM*DM/4);
    cvt_bf16_kernel<<<(DM*DM/4 + 255)/256, 256, 0, stream>>>(W_k, Wcat + 1048576,   DM*DM/4);
    cvt_bf16_kernel<<<(DG*DM/4 + 255)/256, 256, 0, stream>>>(W_v, Wcat + 2097152,   DG*DM/4);
    cvt_bf16_kernel<<<(DG*DM/4 + 255)/256, 256, 0, stream>>>(W_g, Wcat + 4194304,   DG*DM/4);
    cvt_bf16_kernel<<<(DM*DG/4 + 255)/256, 256, 0, stream>>>(W_o, Wo_bf,            DM*DG/4);

    // fused QKVG: M=8192, Ntot=6144, K=1024 -> 768 blocks of 512 (8-phase 256^2)
    gemm_qkvg_8ph<<<(ROWS/256)*(6144/256), 512, 0, stream>>>(
        xbf, Wcat, b_q, b_k, b_v, b_g,
        qry_bf, key_bf, val_bf, gate_bf);

    ret_inner_kernel<<<BATCH*NH*NC, 256, 0, stream>>>(qry_bf, key_bf, val_bf, kvbuf, iscale);
    ret_scan_kernel<<<256, 256, 0, stream>>>(kvbuf, cscale);
    ret_cross_kernel<<<BATCH*NH*NC, 256, 0, stream>>>(qry_bf, kvbuf, val_bf, iscale, cscale,
                                                      gate_bf, gn_g, gn_b);

    // Wo: M=8192, N=1024, K=2048 -> 512 blocks, fp32 out
    gemm_mfma<false><<<(ROWS/128)*(DM/128), 256, 0, stream>>>(
        val_bf, Wo_bf, DG, DM, b_o, nullptr, nullptr, nullptr,
        out, nullptr, nullptr, nullptr);
}

// Round 2
// 648.708 us; speedup vs baseline: 1.0138x; 1.0068x over previous
//
#include <hip/hip_runtime.h>
#include <hip/hip_bf16.h>
#include <math.h>

#define BATCH 2
#define SEQ 4096
#define DM 1024
#define NH 16
#define DK 64
#define DV 128
#define NC 64     // number of chunks
#define CL 64     // chunk length
#define ROWS (BATCH*SEQ)   // 8192
#define DG (DM*2)          // 2048 (val/gate width)

typedef __attribute__((ext_vector_type(8))) short short8;
typedef __attribute__((ext_vector_type(4))) float floatx4;

__device__ __forceinline__ float head_decay(int h) {
    return logf(1.0f - exp2f(-5.0f - (float)h));
}
__device__ __forceinline__ unsigned short bfbits(float v) {
    __hip_bfloat16 h = __float2bfloat16(v);
    return *(unsigned short*)&h;
}
__device__ __forceinline__ float bf2f(unsigned short u) {
    unsigned x = ((unsigned)u) << 16;
    return *(float*)&x;
}
__device__ __forceinline__ unsigned pack2(float a, float b) {
    return (unsigned)bfbits(a) | ((unsigned)bfbits(b) << 16);
}
__device__ __forceinline__ void unpack8(uint4 u, float* dst) {
    dst[0]=bf2f((unsigned short)(u.x&0xffff)); dst[1]=bf2f((unsigned short)(u.x>>16));
    dst[2]=bf2f((unsigned short)(u.y&0xffff)); dst[3]=bf2f((unsigned short)(u.y>>16));
    dst[4]=bf2f((unsigned short)(u.z&0xffff)); dst[5]=bf2f((unsigned short)(u.z>>16));
    dst[6]=bf2f((unsigned short)(u.w&0xffff)); dst[7]=bf2f((unsigned short)(u.w>>16));
}
__device__ __forceinline__ void gld_lds16(const unsigned short* g, unsigned short* l) {
    __builtin_amdgcn_global_load_lds(
        (const __attribute__((address_space(1))) unsigned int*)g,
        (__attribute__((address_space(3))) unsigned int*)l, 16, 0, 0);
}

// barrier WITHOUT the vmcnt(0) drain that __syncthreads() inserts
#define BAR() do { asm volatile("" ::: "memory"); \
    __builtin_amdgcn_s_barrier(); \
    asm volatile("" ::: "memory"); } while(0)
#define BAR_LG() do { asm volatile("" ::: "memory"); \
    __builtin_amdgcn_s_barrier(); \
    asm volatile("s_waitcnt lgkmcnt(0)" ::: "memory"); } while(0)

// ---------------- LN + cast to bf16: one block per row ----------------
__global__ __launch_bounds__(256) void ln_cvt_kernel(const float* __restrict__ x,
        const float* __restrict__ g, const float* __restrict__ b,
        unsigned short* __restrict__ xbf) {
    int row = blockIdx.x;
    const float* xr = x + (size_t)row * DM;
    int c0 = threadIdx.x * 4;
    float4 v = *(const float4*)&xr[c0];
    float s1 = v.x + v.y + v.z + v.w;
    float s2 = v.x*v.x + v.y*v.y + v.z*v.z + v.w*v.w;
#pragma unroll
    for (int off = 32; off > 0; off >>= 1) {
        s1 += __shfl_down(s1, off);
        s2 += __shfl_down(s2, off);
    }
    __shared__ float a1[4], a2[4];
    int wid = threadIdx.x >> 6;
    if ((threadIdx.x & 63) == 0) { a1[wid] = s1; a2[wid] = s2; }
    __syncthreads();
    s1 = a1[0] + a1[1] + a1[2] + a1[3];
    s2 = a2[0] + a2[1] + a2[2] + a2[3];
    float mu = s1 * (1.f/DM);
    float var = s2 * (1.f/DM) - mu*mu;
    float rstd = rsqrtf(var + 1e-5f);
    float o0 = (v.x - mu)*rstd*g[c0+0] + b[c0+0];
    float o1 = (v.y - mu)*rstd*g[c0+1] + b[c0+1];
    float o2 = (v.z - mu)*rstd*g[c0+2] + b[c0+2];
    float o3 = (v.w - mu)*rstd*g[c0+3] + b[c0+3];
    uint2 p; p.x = pack2(o0, o1); p.y = pack2(o2, o3);
    *(uint2*)&xbf[(size_t)row*DM + c0] = p;
}

// ---------------- fp32 -> bf16 weight conversion ----------------
__global__ __launch_bounds__(256) void cvt_bf16_kernel(const float* __restrict__ src,
        unsigned short* __restrict__ dst, int n4) {
    int i = blockIdx.x * 256 + threadIdx.x;
    if (i < n4) {
        float4 v = ((const float4*)src)[i];
        uint2 p; p.x = pack2(v.x, v.y); p.y = pack2(v.z, v.w);
        ((uint2*)dst)[i] = p;
    }
}

// ============ QKVG GEMM: 256x256 tile, BK=64, 8-wave, 8-phase counted-vmcnt ============
// A(8192x1024,bf16) x Wcat(6144x1024,bf16)^T. 768 blocks of 512 threads, 128 KiB LDS.
// KEY FIX vs prior round: the four tile buffers are FOUR SEPARATE __shared__ arrays.
// With one monolithic array, LLVM's SIInsertWaitcnts treats every ds_read as
// MayAlias with every in-flight global_load_lds (LDS-DMA tracking) and inserts an
// effective vmcnt(0) drain per phase -- defeating the counted-vmcnt pipeline
// (observed: MfmaUtil 16%, no speedup vs 2-barrier). Distinct arrays give the
// alias analysis distinct underlying objects; the pass's inserted waits then
// coincide with the intended counted schedule (all runtime-satisfied).
// Each buffer 256x64 bf16; 16B-block XOR swizzle: block bl of row r holds global
// k-block bl^(r&7). Iteration i computes K-tiles 2i (buf0, P1-P4) and 2i+1
// (buf1, P5-P8); per wave 128x64 output = acc[8][4], 16 MFMA/phase.
// Half-tile stage schedule (race-free: each stage is issued >=1 barrier after the
// target region's last ds_read, and vmcnt(4)+barrier at P4/P8 guarantees landing
// before first consume; vmcnt is NEVER 0 in the loop):
//   P1: B(2i+1)h0->Bb1   P2: B(2i+1)h1   P3: B(2i+2)h0->Bb0  P4: B(2i+2)h1, vmcnt(4)
//   P5: A(2i+2)h0->Ab0   P6: A(2i+2)h1   P7: --              P8: A(2i+3)h0+h1->Ab1, vmcnt(4)
// Reads: P1/P5: A[m0-3]+B[n0-1] (12xb128); P2/P6: B[n2-3]; P3/P7: A[m4-7]; P4/P8: none.
// Last iteration stages tiles >=nkt: lands in buffers after their final reads and
// is never consumed; addresses overrun K into adjacent ws regions (safe).
// Epilogue reuses Ab0 ([64][256] bf16 = 32 KB) -- disjoint from the still-
// outstanding tail stage (targets Ab1); the epilogue __syncthreads drains it.
__global__ __launch_bounds__(512, 2) void gemm_qkvg_8ph(
        const unsigned short* __restrict__ A, const unsigned short* __restrict__ W,
        const float* __restrict__ b0, const float* __restrict__ b1,
        const float* __restrict__ b2, const float* __restrict__ b3,
        unsigned short* __restrict__ o0, unsigned short* __restrict__ o1,
        unsigned short* __restrict__ o2, unsigned short* __restrict__ o3) {
    constexpr int KK  = DM;         // 1024
    constexpr int NIT = KK / 128;   // 8 iterations x 2 K-tiles
    __shared__ __align__(16) unsigned short Ab0[16384];
    __shared__ __align__(16) unsigned short Ab1[16384];
    __shared__ __align__(16) unsigned short Bb0[16384];
    __shared__ __align__(16) unsigned short Bb1[16384];

    // XCD-contiguous raster (768 % 8 == 0 -> simple swizzle is bijective),
    // then 4 bm x 24 bn groups per XCD for L2 reuse.
    const int nbn = 6144 >> 8;                 // 24
    const int nb  = (ROWS >> 8) * nbn;         // 768
    const int per = nb >> 3;                   // 96
    int id = blockIdx.x;
    int logical = (id & 7) * per + (id >> 3);
    const int in_grp = 4 * nbn;                // 96
    int g   = logical / in_grp;
    int rem = logical - g * in_grp;
    const int bm = (g * 4 + (rem & 3)) << 8;
    const int bn = (rem >> 2) << 8;

    const int tid  = threadIdx.x;
    const int lane = tid & 63;
    const int wave = tid >> 6;
    const int warp_m = wave >> 2, warp_n = wave & 3;   // 2 x 4 wave grid
    const int fm = lane & 15, kq = lane >> 4;

    // staging map: row = tid>>3 (64 rows/round), 16B block (tid&7) holds global
    // block (tid&7)^(row&7); global_load_lds dest = linear base + tid*16B.
    const int srow = tid >> 3;
    const int scol = ((tid & 7) ^ (srow & 7)) * 8;
    const unsigned short* Asrc = A + (size_t)(bm + srow) * KK + scol;
    const unsigned short* Wsrc = W + (size_t)(bn + srow) * KK + scol;

    int kcol[2];
#pragma unroll
    for (int ks = 0; ks < 2; ks++) kcol[ks] = ((ks*4 + kq) ^ (fm & 7)) * 8;
    const int afm = warp_m * 8192 + fm * 64;
    const int bfm = warp_n * 4096 + fm * 64;

    floatx4 acc[8][4] = {};
    short8 aF[8], bF[8];

    auto stageHalf = [&](unsigned short* dst, const unsigned short* gsrc) {
        gld_lds16(gsrc,          dst + tid*8);
        gld_lds16(gsrc + 64*KK,  dst + 4096 + tid*8);
    };
    auto rdA = [&](const unsigned short* buf, int mi0) {
#pragma unroll
        for (int mi = 0; mi < 4; mi++)
#pragma unroll
            for (int ks = 0; ks < 2; ks++)
                aF[mi*2+ks] = *(const short8*)&buf[afm + (mi0+mi)*1024 + kcol[ks]];
    };
    auto rdB = [&](const unsigned short* buf, int ni0) {
#pragma unroll
        for (int ni = 0; ni < 2; ni++)
#pragma unroll
            for (int ks = 0; ks < 2; ks++)
                bF[(ni0+ni)*2+ks] = *(const short8*)&buf[bfm + (ni0+ni)*1024 + kcol[ks]];
    };
    auto mma = [&](int mi0, int ni0) {
        __builtin_amdgcn_s_setprio(1);
#pragma unroll
        for (int mi = 0; mi < 4; mi++)
#pragma unroll
            for (int ni = 0; ni < 2; ni++)
#pragma unroll
                for (int ks = 0; ks < 2; ks++)
                    acc[mi0+mi][ni0+ni] = __builtin_amdgcn_mfma_f32_16x16x32_bf16(
                        aF[mi*2+ks], bF[(ni0+ni)*2+ks], acc[mi0+mi][ni0+ni], 0, 0, 0);
        __builtin_amdgcn_s_setprio(0);
    };

    // ---- prologue: A(0),B(0) -> buf0 (8 loads); A(1) -> Ab1 (4 loads) ----
    stageHalf(Ab0,        Asrc);
    stageHalf(Ab0 + 8192, Asrc + 128*KK);
    stageHalf(Bb0,        Wsrc);
    stageHalf(Bb0 + 8192, Wsrc + 128*KK);
    stageHalf(Ab1,        Asrc + 64);
    stageHalf(Ab1 + 8192, Asrc + 128*KK + 64);
    asm volatile("s_waitcnt vmcnt(4)" ::: "memory");   // A0,B0 landed; A1 in flight
    BAR();

#pragma unroll 1
    for (int i = 0; i < NIT; i++) {
        const int kB1 = (2*i + 1) * 64;
        const int kN  = (2*i + 2) * 64;
        // ---- P1 (tile 2i, buf0) ----
        rdA(Ab0, 0); rdB(Bb0, 0);
        stageHalf(Bb1, Wsrc + kB1);
        BAR_LG();
        mma(0, 0);
        BAR();
        // ---- P2 ----
        rdB(Bb0, 2);
        stageHalf(Bb1 + 8192, Wsrc + 128*KK + kB1);
        BAR_LG();
        mma(0, 2);
        BAR();
        // ---- P3 ----
        rdA(Ab0, 4);
        stageHalf(Bb0, Wsrc + kN);
        BAR_LG();
        mma(4, 0);
        BAR();
        // ---- P4 ----
        stageHalf(Bb0 + 8192, Wsrc + 128*KK + kN);
        BAR_LG();
        mma(4, 2);
        asm volatile("s_waitcnt vmcnt(4)" ::: "memory"); // A(2i+1),B(2i+1) landed
        BAR();
        // ---- P5 (tile 2i+1, buf1) ----
        rdA(Ab1, 0); rdB(Bb1, 0);
        stageHalf(Ab0, Asrc + kN);
        BAR_LG();
        mma(0, 0);
        BAR();
        // ---- P6 ----
        rdB(Bb1, 2);
        stageHalf(Ab0 + 8192, Asrc + 128*KK + kN);
        BAR_LG();
        mma(0, 2);
        BAR();
        // ---- P7 ----
        rdA(Ab1, 4);
        BAR_LG();
        mma(4, 0);
        BAR();
        // ---- P8 ----
        stageHalf(Ab1,        Asrc + kN + 64);
        stageHalf(Ab1 + 8192, Asrc + 128*KK + kN + 64);
        BAR_LG();
        mma(4, 2);
        asm volatile("s_waitcnt vmcnt(4)" ::: "memory"); // A(2i+2),B(2i+2) landed
        BAR();
    }

    // ---- segment routing + epilogue through Ab0 ([64][256] bf16) ----
    int seg = bn >> 10;
    unsigned short* obf; const float* bias; int No, lcb; bool doRope = false; float scale = 1.f;
    if (seg == 0)      { obf = o0; bias = b0; No = 1024; lcb = bn;        doRope = true; }
    else if (seg == 1) { obf = o1; bias = b1; No = 1024; lcb = bn - 1024; doRope = true; scale = 0.125f; }
    else if (seg <= 3) { obf = o2; bias = b2; No = 2048; lcb = bn - 2048; }
    else               { obf = o3; bias = b3; No = 2048; lcb = bn - 4096; }

    const int crow = (lane >> 4) * 4, ccol = lane & 15;
    for (int pass = 0; pass < 4; pass++) {
        if (warp_m == (pass >> 1)) {              // wave-uniform
            int mi0 = (pass & 1) * 4;
#pragma unroll
            for (int mi = 0; mi < 4; mi++) {
#pragma unroll
                for (int ni = 0; ni < 4; ni++) {
                    int tcol = warp_n*64 + ni*16 + ccol;
                    float bcol = bias[lcb + tcol];
#pragma unroll
                    for (int r = 0; r < 4; r++) {
                        int gr = warp_m*128 + (mi0+mi)*16 + crow + r;
                        float v = (acc[mi0+mi][ni][r] + bcol) * scale;
                        if (doRope) {
                            float vp = __shfl_xor(v, 1);   // partner col (tcol^1)
                            int s = (bm + gr) & (SEQ-1);
                            int jj = (tcol & 63) >> 1;
                            float ang = exp2f(-(float)jj * (13.287712379549449f/31.f));
                            float sn, cs;
                            sincosf((float)s * ang, &sn, &cs);
                            v = (tcol & 1) ? (v*cs + vp*sn) : (v*cs - vp*sn);
                        }
                        Ab0[(gr & 63)*256 + tcol] = bfbits(v);
                    }
                }
            }
        }
        __syncthreads();
        {   // 64 rows x 512B; 512 thr x 16B = 16 rows/round, 4 rounds
            int rrow = tid >> 5, rc = (tid & 31) * 8;
#pragma unroll
            for (int it = 0; it < 4; it++) {
                int lr = it*16 + rrow;
                uint4 u = *(const uint4*)&Ab0[lr*256 + rc];
                *(uint4*)&obf[(size_t)(bm + pass*64 + lr)*No + lcb + rc] = u;
            }
        }
        __syncthreads();
    }
}

// ---------------- bf16 MFMA NT GEMM, 128x128 tile, BK=64, XOR-swizzled LDS ----------------
// (retained for the Wo GEMM; QKVG path moved to gemm_qkvg_8ph above)
template<bool QKVG>
__global__ __launch_bounds__(256) void gemm_mfma(
        const unsigned short* __restrict__ A, const unsigned short* __restrict__ W,
        int K, int Ntot,
        const float* __restrict__ b0, const float* __restrict__ b1,
        const float* __restrict__ b2, const float* __restrict__ b3,
        void* __restrict__ o0, void* __restrict__ o1,
        void* __restrict__ o2, void* __restrict__ o3) {
    const int nbn = Ntot >> 7;
    const int nb  = (ROWS >> 7) * nbn;
    const int per = nb >> 3;
    int id = blockIdx.x;
    int logical = (id & 7) * per + (id >> 3);
    const int in_grp = 8 * nbn;
    int g   = logical / in_grp;
    int rem = logical - g * in_grp;
    const int bm = (g * 8 + (rem & 7)) << 7;
    const int bn = (rem >> 3) << 7;

    __shared__ unsigned short smem[16384];     // 32 KB: As[128][64] | Bs[128][64]; epi aliases
    unsigned short* As = smem;
    unsigned short* Bs = smem + 8192;

    const int tid = threadIdx.x;
    const int wave = tid >> 6, lane = tid & 63;
    const int wm = (wave & 1) * 64, wn = (wave >> 1) * 64;

    const int sr = tid >> 3;
    const int scol = (((tid & 7) ^ (sr & 7)) * 8);
    const unsigned short* Ag = A + (size_t)(bm + sr) * K + scol;
    const unsigned short* Wg = W + (size_t)(bn + sr) * K + scol;
    const int fm = lane & 15;
    const int kq = lane >> 4;

    floatx4 acc[4][4] = {};
    for (int k0 = 0; k0 < K; k0 += 64) {
#pragma unroll
        for (int t = 0; t < 4; t++) {
            gld_lds16(Ag + (size_t)(t*32)*K + k0, &As[t*2048 + tid*8]);
            gld_lds16(Wg + (size_t)(t*32)*K + k0, &Bs[t*2048 + tid*8]);
        }
        __syncthreads();
#pragma unroll
        for (int half = 0; half < 2; half++) {
            const int kb = half*4 + kq;
            short8 af[4], bfv[4];
#pragma unroll
            for (int mi = 0; mi < 4; mi++) {
                int r = wm + mi*16 + fm;
                af[mi] = *(const short8*)&As[r*64 + ((kb ^ (r & 7))*8)];
            }
#pragma unroll
            for (int ni = 0; ni < 4; ni++) {
                int r = wn + ni*16 + fm;
                bfv[ni] = *(const short8*)&Bs[r*64 + ((kb ^ (r & 7))*8)];
            }
#pragma unroll
            for (int mi = 0; mi < 4; mi++)
#pragma unroll
                for (int ni = 0; ni < 4; ni++)
                    acc[mi][ni] = __builtin_amdgcn_mfma_f32_16x16x32_bf16(
                                      af[mi], bfv[ni], acc[mi][ni], 0, 0, 0);
        }
        __syncthreads();
    }

    float scale = 1.f; bool doRope = false;
    const float* bias; int No, lcb;
    unsigned short* obf = nullptr; float* of32 = nullptr;
    if (QKVG) {
        int seg = bn >> 10;
        if (seg == 0)      { obf = (unsigned short*)o0; bias = b0; No = 1024; lcb = bn;        doRope = true; }
        else if (seg == 1) { obf = (unsigned short*)o1; bias = b1; No = 1024; lcb = bn - 1024; doRope = true; scale = 0.125f; }
        else if (seg <= 3) { obf = (unsigned short*)o2; bias = b2; No = 2048; lcb = bn - 2048; }
        else               { obf = (unsigned short*)o3; bias = b3; No = 2048; lcb = bn - 4096; }
    } else {
        of32 = (float*)o0; bias = b0; No = Ntot; lcb = bn;
    }

    const int crow = (lane >> 4) * 4, ccol = lane & 15;
    unsigned short* epib = smem;
    float* epif = (float*)smem;
    for (int pass = 0; pass < 2; pass++) {
#pragma unroll
        for (int mi = 0; mi < 4; mi++) {
            if (((wm + mi*16) >> 6) != pass) continue;
#pragma unroll
            for (int ni = 0; ni < 4; ni++) {
                int tcol = wn + ni*16 + ccol;
                float bcol = bias[lcb + tcol];
#pragma unroll
                for (int r = 0; r < 4; r++) {
                    int gr = wm + mi*16 + crow + r;
                    float v = (acc[mi][ni][r] + bcol) * scale;
                    if (QKVG) {
                        if (doRope) {
                            float vp = __shfl_xor(v, 1);
                            int s = (bm + gr) & (SEQ-1);
                            int jj = (tcol & 63) >> 1;
                            float ang = exp2f(-(float)jj * (13.287712379549449f/31.f));
                            float sn, cs;
                            sincosf((float)s * ang, &sn, &cs);
                            v = (tcol & 1) ? (v*cs + vp*sn) : (v*cs - vp*sn);
                        }
                        epib[(gr & 63)*128 + tcol] = bfbits(v);
                    } else {
                        epif[(gr & 63)*128 + tcol] = v;
                    }
                }
            }
        }
        __syncthreads();
        if (QKVG) {
            int rrow = tid >> 4, rc = (tid & 15) * 8;
#pragma unroll
            for (int it = 0; it < 4; it++) {
                int lr = it*16 + rrow;
                uint4 u = *(const uint4*)&epib[lr*128 + rc];
                *(uint4*)&obf[(size_t)(bm + pass*64 + lr)*No + lcb + rc] = u;
            }
        } else {
            int rrow = tid >> 5, rc = (tid & 31) * 4;
#pragma unroll
            for (int it = 0; it < 8; it++) {
                int lr = it*8 + rrow;
                uint4 u = *(const uint4*)&epif[lr*128 + rc];
                *(uint4*)&of32[(size_t)(bm + pass*64 + lr)*No + lcb + rc] = u;
            }
        }
        __syncthreads();
    }
}

// ---------------- retention per-chunk (bf16 in, inner_out in-place bf16, KV fp32) ----------------
__global__ __launch_bounds__(256) void ret_inner_kernel(
        const unsigned short* __restrict__ qry, const unsigned short* __restrict__ key,
        unsigned short* __restrict__ valio, float* __restrict__ kv_out,
        float* __restrict__ iscale_out) {
    int blk = blockIdx.x;
    int c = blk & 63;
    int h = (blk >> 6) & 15;
    int b = blk >> 10;
    float dec = head_decay(h);

    __shared__ float uni[64*65];
    __shared__ float Ks[CL][DK+1];
    __shared__ float Ss[CL][CL+1];
    __shared__ float ascale[CL];
    __shared__ float iscale[CL];

    int tid = threadIdx.x;
    size_t qkbase = ((size_t)(b*SEQ + c*CL))*DM + (size_t)h*DK;
#pragma unroll
    for (int it = 0; it < 2; it++) {
        int s = tid + it*256;
        int i = s >> 3, c0 = (s & 7)*8;
        uint4 uq = *(const uint4*)&qry[qkbase + (size_t)i*DM + c0];
        uint4 uk = *(const uint4*)&key[qkbase + (size_t)i*DM + c0];
        unpack8(uq, &uni[i*65 + c0]);
        unpack8(uk, &Ks[i][c0]);
    }
    if (tid < CL) {
        float ssum = 0.f;
        for (int t = 0; t <= tid; t++) ssum += expf(dec * (float)t);
        ascale[tid] = sqrtf(ssum);
    }
    __syncthreads();

    {
        int tx = tid & 15, ty = tid >> 4;
        float acc[4][4] = {};
        for (int d = 0; d < DK; d++) {
            float av[4], bv[4];
#pragma unroll
            for (int i = 0; i < 4; i++) av[i] = uni[(ty*4+i)*65 + d];
#pragma unroll
            for (int j = 0; j < 4; j++) bv[j] = Ks[tx*4+j][d];
#pragma unroll
            for (int i = 0; i < 4; i++)
#pragma unroll
                for (int j = 0; j < 4; j++)
                    acc[i][j] += av[i]*bv[j];
        }
#pragma unroll
        for (int i = 0; i < 4; i++) {
            int ri = ty*4 + i;
            float ra = 1.f / ascale[ri];
#pragma unroll
            for (int j = 0; j < 4; j++) {
                int cj = tx*4 + j;
                float m = (cj <= ri) ? expf(dec*(float)(ri-cj)) * ra : 0.f;
                Ss[ri][cj] = acc[i][j] * m;
            }
        }
    }
    __syncthreads();
    if (tid < CL) {
        float rs = 0.f;
        for (int j = 0; j < CL; j++) rs += Ss[tid][j];
        float isc = fmaxf(fabsf(rs), 1.f);
        iscale[tid] = isc;
        iscale_out[(size_t)blk*CL + tid] = isc;
    }

    int txv = tid & 15, tyv = tid >> 4;
    int v0 = txv*4, i0 = tyv*4;
    size_t vbase = ((size_t)(b*SEQ + c*CL))*DG + (size_t)h*DV;
    for (int half = 0; half < 2; half++) {
        __syncthreads();
#pragma unroll
        for (int it = 0; it < 2; it++) {
            int s = tid + it*256;
            int i = s >> 3, c0 = (s & 7)*8;
            uint4 uv = *(const uint4*)&valio[vbase + (size_t)i*DG + half*64 + c0];
            unpack8(uv, &uni[i*64 + c0]);
        }
        __syncthreads();
        float acc2[4][4] = {};
        float acc3[4][4] = {};
        for (int j = 0; j < CL; j++) {
            float4 vv = *(const float4*)&uni[j*64 + v0];
            float va[4] = {vv.x, vv.y, vv.z, vv.w};
#pragma unroll
            for (int r = 0; r < 4; r++) {
                float s  = Ss[i0+r][j];
                float kk = Ks[j][i0+r];
#pragma unroll
                for (int q = 0; q < 4; q++) {
                    acc2[r][q] += s*va[q];
                    acc3[r][q] += kk*va[q];
                }
            }
        }
#pragma unroll
        for (int r = 0; r < 4; r++) {
            int i = i0 + r;
            float inv = 1.f / iscale[i];
            uint2 p;
            p.x = pack2(acc2[r][0]*inv, acc2[r][1]*inv);
            p.y = pack2(acc2[r][2]*inv, acc2[r][3]*inv);
            *(uint2*)&valio[vbase + (size_t)i*DG + half*64 + v0] = p;
            float4 kvo = make_float4(acc3[r][0], acc3[r][1], acc3[r][2], acc3[r][3]);
            *(float4*)&kv_out[(size_t)blk*(DK*DV) + (size_t)i*DV + half*64 + v0] = kvo;
        }
    }
}

// ---------------- sequential scan over chunks (in-place KV -> cross_chunk) ----------------
__global__ __launch_bounds__(256) void ret_scan_kernel(float* __restrict__ kv,
        float* __restrict__ cscale_out) {
    int tid = threadIdx.x;
    int col = blockIdx.x*16 + ((tid >> 6) << 2) + (tid & 3);
    int kp  = (tid >> 2) & 15;
    int v   = col & 127;
    int bh  = col >> 7;
    int h   = bh & 15;
    float dec = head_decay(h);
    float cdecay = expf(dec * (float)CL);
    float state[4] = {0.f, 0.f, 0.f, 0.f};
    float scale = 1.f;
    size_t base0 = (size_t)bh*NC*(DK*DV) + (size_t)(kp*4)*DV + v;
    float cur[4];
#pragma unroll
    for (int kk = 0; kk < 4; kk++) cur[kk] = kv[base0 + (size_t)kk*DV];
    for (int c = 0; c < NC; c++) {
        size_t base = base0 + (size_t)c*(DK*DV);
        float nxt[4];
        if (c+1 < NC) {
            size_t nb = base + (size_t)(DK*DV);
#pragma unroll
            for (int kk = 0; kk < 4; kk++) nxt[kk] = kv[nb + (size_t)kk*DV];
        }
        float inv = 1.f / scale;
#pragma unroll
        for (int kk = 0; kk < 4; kk++) kv[base + (size_t)kk*DV] = cur[kk]*inv;
        if (kp == 0) cscale_out[((size_t)bh*NC + c)*DV + v] = scale;
        float ssum = 0.f;
#pragma unroll
        for (int kk = 0; kk < 4; kk++) {
            state[kk] = state[kk]*cdecay + cur[kk];
            ssum += fabsf(state[kk]);
        }
        ssum += __shfl_xor(ssum, 4);
        ssum += __shfl_xor(ssum, 8);
        ssum += __shfl_xor(ssum, 16);
        ssum += __shfl_xor(ssum, 32);
        scale = fmaxf(ssum, 1.f);
        if (c+1 < NC) {
#pragma unroll
            for (int kk = 0; kk < 4; kk++) cur[kk] = nxt[kk];
        }
    }
}

// ---------------- cross_out + combine + groupnorm + silu(gate), in-place bf16 ----------------
__global__ __launch_bounds__(256) void ret_cross_kernel(
        const unsigned short* __restrict__ qry, const float* __restrict__ cross_chunk,
        unsigned short* __restrict__ valio, const float* __restrict__ iscale,
        const float* __restrict__ cscale, const unsigned short* __restrict__ gatebf,
        const float* __restrict__ gn_g, const float* __restrict__ gn_b) {
    int blk = blockIdx.x;
    int c = blk & 63, h = (blk >> 6) & 15, b = blk >> 10;
    float dec = head_decay(h);
    __shared__ float Qs[CL][DK+1];
    __shared__ float CC[DK][DV];
    __shared__ float asc[CL];
    __shared__ float idec[CL];

    int tid = threadIdx.x;
    size_t qbase = ((size_t)(b*SEQ + c*CL))*DM + (size_t)h*DK;
#pragma unroll
    for (int it = 0; it < 2; it++) {
        int s = tid + it*256;
        int i = s >> 3, c0 = (s & 7)*8;
        uint4 uq = *(const uint4*)&qry[qbase + (size_t)i*DM + c0];
        unpack8(uq, &Qs[i][c0]);
    }
    size_t cbase = (size_t)blk * (DK*DV);
#pragma unroll
    for (int t = 0; t < 32; t++) {
        int idx = tid + t*256;
        CC[idx >> 7][idx & 127] = cross_chunk[cbase + idx];
    }
    if (tid < CL) {
        float ssum = 0.f;
        for (int t = 0; t <= tid; t++) ssum += expf(dec * (float)t);
        asc[tid] = sqrtf(ssum);
    }
    __syncthreads();
    if (tid < CL) idec[tid] = expf(dec*(float)(tid+1)) * asc[CL-1] / asc[tid];
    __syncthreads();

    int txv = tid & 31, tyv = tid >> 5;
    int v0 = txv*4, i0 = tyv*8;
    float acc[8][4] = {};
    for (int k = 0; k < DK; k++) {
        float4 cv = *(const float4*)&CC[k][v0];
        float ca[4] = {cv.x, cv.y, cv.z, cv.w};
#pragma unroll
        for (int r = 0; r < 8; r++) {
            float qv = Qs[i0+r][k];
#pragma unroll
            for (int q = 0; q < 4; q++) acc[r][q] += qv*ca[q];
        }
    }
    float4 csv = *(const float4*)&cscale[(size_t)blk*DV + v0];
    float csa[4] = {csv.x, csv.y, csv.z, csv.w};
    float o[8][4];
    float s1[8], s2[8];
#pragma unroll
    for (int r = 0; r < 8; r++) {
        int i = i0 + r;
        float f2 = idec[i] / iscale[(size_t)blk*CL + i];
        size_t orow = ((size_t)(b*SEQ + c*CL + i))*DG + (size_t)h*DV + v0;
        uint2 iu = *(const uint2*)&valio[orow];
        float ioa[4] = { bf2f((unsigned short)(iu.x & 0xffff)),
                         bf2f((unsigned short)(iu.x >> 16)),
                         bf2f((unsigned short)(iu.y & 0xffff)),
                         bf2f((unsigned short)(iu.y >> 16)) };
        float rs1 = 0.f, rs2 = 0.f;
#pragma unroll
        for (int q = 0; q < 4; q++) {
            float ov = ioa[q]/csa[q] + acc[r][q]*f2;
            o[r][q] = ov;
            rs1 += ov; rs2 += ov*ov;
        }
        s1[r] = rs1; s2[r] = rs2;
    }
#pragma unroll
    for (int r = 0; r < 8; r++) {
#pragma unroll
        for (int m = 1; m <= 16; m <<= 1) {
            s1[r] += __shfl_xor(s1[r], m);
            s2[r] += __shfl_xor(s2[r], m);
        }
    }
#pragma unroll
    for (int r = 0; r < 8; r++) {
        int i = i0 + r;
        float mu = s1[r] * (1.f/DV);
        float var = s2[r] * (1.f/DV) - mu*mu;
        float rstd = rsqrtf(var + 1e-5f);
        size_t orow = ((size_t)(b*SEQ + c*CL + i))*DG + (size_t)h*DV + v0;
        uint2 gu = *(const uint2*)&gatebf[orow];
        float ga[4] = { bf2f((unsigned short)(gu.x & 0xffff)),
                        bf2f((unsigned short)(gu.x >> 16)),
                        bf2f((unsigned short)(gu.y & 0xffff)),
                        bf2f((unsigned short)(gu.y >> 16)) };
        float res[4];
#pragma unroll
        for (int q = 0; q < 4; q++) {
            int col = h*DV + v0 + q;
            float xn = (o[r][q] - mu)*rstd*gn_g[col] + gn_b[col];
            float sg = ga[q] / (1.f + expf(-ga[q]));
            res[q] = xn * sg;
        }
        uint2 p; p.x = pack2(res[0], res[1]); p.y = pack2(res[2], res[3]);
        *(uint2*)&valio[orow] = p;
    }
}

extern "C" void kernel_launch(void* const* d_in, const int* in_sizes, int n_in,
                              void* d_out, int out_size, void* d_ws, size_t ws_size,
                              hipStream_t stream) {
    (void)in_sizes; (void)n_in; (void)out_size; (void)ws_size;
    const float* x    = (const float*)d_in[0];
    const float* W_q  = (const float*)d_in[2];
    const float* b_q  = (const float*)d_in[3];
    const float* W_k  = (const float*)d_in[4];
    const float* b_k  = (const float*)d_in[5];
    const float* W_v  = (const float*)d_in[6];
    const float* b_v  = (const float*)d_in[7];
    const float* W_g  = (const float*)d_in[8];
    const float* b_g  = (const float*)d_in[9];
    const float* W_o  = (const float*)d_in[10];
    const float* b_o  = (const float*)d_in[11];
    const float* ln_g = (const float*)d_in[12];
    const float* ln_b = (const float*)d_in[13];
    const float* gn_g = (const float*)d_in[14];
    const float* gn_b = (const float*)d_in[15];
    float* out = (float*)d_out;
    float* ws  = (float*)d_ws;

    // workspace layout (floats) — total ~39.2M floats = 157 MB
    float* keyb   = ws;                       //  4,194,304 (bf16 key 8192x1024)
    float* valb   = keyb   + 4194304;         //  8,388,608 (bf16 val->inner_out->acts 8192x2048)
    float* gateb  = valb   + 8388608;         //  8,388,608 (bf16 gate)
    float* kvbuf  = gateb  + 8388608;         // 16,777,216 fp32 KV->cross_chunk
    float* iscale = kvbuf  + 16777216;        //    131,072
    float* cscale = iscale + 131072;          //    262,144
    float* wobuf  = cscale + 262144;          //  1,048,576 (bf16 W_o 1024x2048)

    unsigned short* xbf  = (unsigned short*)kvbuf;             // 8,388,608 bf16
    unsigned short* Wcat = (unsigned short*)(kvbuf + 4194304); // 6,291,456 bf16 (6144x1024)
    unsigned short* Wo_bf  = (unsigned short*)wobuf;
    unsigned short* key_bf = (unsigned short*)keyb;
    unsigned short* val_bf = (unsigned short*)valb;
    unsigned short* gate_bf= (unsigned short*)gateb;
    unsigned short* qry_bf = (unsigned short*)out;   // d_out doubles as bf16 qry scratch

    ln_cvt_kernel<<<ROWS, 256, 0, stream>>>(x, ln_g, ln_b, xbf);
    cvt_bf16_kernel<<<(DM*DM/4 + 255)/256, 256, 0, stream>>>(W_q, Wcat,             DM*DM/4);
    cvt_bf16_kernel<<<(DM*DM/4 + 255)/256, 256, 0, stream>>>(W_k, Wcat + 1048576,   DM*DM/4);
    cvt_bf16_kernel<<<(DG*DM/4 + 255)/256, 256, 0, stream>>>(W_v, Wcat + 2097152,   DG*DM/4);
    cvt_bf16_kernel<<<(DG*DM/4 + 255)/256, 256, 0, stream>>>(W_g, Wcat + 4194304,   DG*DM/4);
    cvt_bf16_kernel<<<(DM*DG/4 + 255)/256, 256, 0, stream>>>(W_o, Wo_bf,            DM*DG/4);

    // fused QKVG: M=8192, Ntot=6144, K=1024 -> 768 blocks of 512 (8-phase 256^2)
    gemm_qkvg_8ph<<<(ROWS/256)*(6144/256), 512, 0, stream>>>(
        xbf, Wcat, b_q, b_k, b_v, b_g,
        qry_bf, key_bf, val_bf, gate_bf);

    ret_inner_kernel<<<BATCH*NH*NC, 256, 0, stream>>>(qry_bf, key_bf, val_bf, kvbuf, iscale);
    ret_scan_kernel<<<256, 256, 0, stream>>>(kvbuf, cscale);
    ret_cross_kernel<<<BATCH*NH*NC, 256, 0, stream>>>(qry_bf, kvbuf, val_bf, iscale, cscale,
                                                      gate_bf, gn_g, gn_b);

    // Wo: M=8192, N=1024, K=2048 -> 512 blocks, fp32 out
    gemm_mfma<false><<<(ROWS/128)*(DM/128), 256, 0, stream>>>(
        val_bf, Wo_bf, DG, DM, b_o, nullptr, nullptr, nullptr,
        out, nullptr, nullptr, nullptr);
}

// Round 3
// 645.758 us; speedup vs baseline: 1.0185x; 1.0046x over previous
//
#include <hip/hip_runtime.h>
#include <hip/hip_bf16.h>
#include <math.h>

#define BATCH 2
#define SEQ 4096
#define DM 1024
#define NH 16
#define DK 64
#define DV 128
#define NC 64     // number of chunks
#define CL 64     // chunk length
#define ROWS (BATCH*SEQ)   // 8192
#define DG (DM*2)          // 2048 (val/gate width)

typedef __attribute__((ext_vector_type(8))) short short8;
typedef __attribute__((ext_vector_type(4))) float floatx4;

__device__ __forceinline__ float head_decay(int h) {
    return logf(1.0f - exp2f(-5.0f - (float)h));
}
__device__ __forceinline__ unsigned short bfbits(float v) {
    __hip_bfloat16 h = __float2bfloat16(v);
    return *(unsigned short*)&h;
}
__device__ __forceinline__ float bf2f(unsigned short u) {
    unsigned x = ((unsigned)u) << 16;
    return *(float*)&x;
}
__device__ __forceinline__ unsigned pack2(float a, float b) {
    return (unsigned)bfbits(a) | ((unsigned)bfbits(b) << 16);
}
__device__ __forceinline__ void unpack8(uint4 u, float* dst) {
    dst[0]=bf2f((unsigned short)(u.x&0xffff)); dst[1]=bf2f((unsigned short)(u.x>>16));
    dst[2]=bf2f((unsigned short)(u.y&0xffff)); dst[3]=bf2f((unsigned short)(u.y>>16));
    dst[4]=bf2f((unsigned short)(u.z&0xffff)); dst[5]=bf2f((unsigned short)(u.z>>16));
    dst[6]=bf2f((unsigned short)(u.w&0xffff)); dst[7]=bf2f((unsigned short)(u.w>>16));
}
__device__ __forceinline__ void gld_lds16(const unsigned short* g, unsigned short* l) {
    __builtin_amdgcn_global_load_lds(
        (const __attribute__((address_space(1))) unsigned int*)g,
        (__attribute__((address_space(3))) unsigned int*)l, 16, 0, 0);
}
// LDS byte offset of a __shared__ pointer (AS3 pointers are 32-bit offsets)
__device__ __forceinline__ unsigned ldsoff(unsigned short* p) {
    return (unsigned)(unsigned long long)(__attribute__((address_space(3))) unsigned short*)p;
}
// inline-asm ds_read_b128: invisible to SIInsertWaitcnts' LDS-DMA alias tracking,
// so the compiler cannot insert conservative vmcnt drains before it. Completion
// ordering is 100% on our manual s_waitcnt lgkmcnt(0) + sched_barrier(0).
template<int IMM>
__device__ __forceinline__ short8 dsr128(unsigned addr) {
    short8 r;
    asm volatile("ds_read_b128 %0, %1 offset:%2" : "=v"(r) : "v"(addr), "i"(IMM));
    return r;
}

// barrier WITHOUT the vmcnt(0) drain that __syncthreads() inserts
#define BAR() do { asm volatile("" ::: "memory"); \
    __builtin_amdgcn_s_barrier(); \
    asm volatile("" ::: "memory"); } while(0)
// barrier + wait for our asm ds_reads; sched_barrier stops MFMA hoisting (rule #18)
#define BAR_LG() do { asm volatile("" ::: "memory"); \
    __builtin_amdgcn_s_barrier(); \
    asm volatile("s_waitcnt lgkmcnt(0)" ::: "memory"); \
    __builtin_amdgcn_sched_barrier(0); } while(0)

// ---------------- LN + cast to bf16: one block per row ----------------
__global__ __launch_bounds__(256) void ln_cvt_kernel(const float* __restrict__ x,
        const float* __restrict__ g, const float* __restrict__ b,
        unsigned short* __restrict__ xbf) {
    int row = blockIdx.x;
    const float* xr = x + (size_t)row * DM;
    int c0 = threadIdx.x * 4;
    float4 v = *(const float4*)&xr[c0];
    float s1 = v.x + v.y + v.z + v.w;
    float s2 = v.x*v.x + v.y*v.y + v.z*v.z + v.w*v.w;
#pragma unroll
    for (int off = 32; off > 0; off >>= 1) {
        s1 += __shfl_down(s1, off);
        s2 += __shfl_down(s2, off);
    }
    __shared__ float a1[4], a2[4];
    int wid = threadIdx.x >> 6;
    if ((threadIdx.x & 63) == 0) { a1[wid] = s1; a2[wid] = s2; }
    __syncthreads();
    s1 = a1[0] + a1[1] + a1[2] + a1[3];
    s2 = a2[0] + a2[1] + a2[2] + a2[3];
    float mu = s1 * (1.f/DM);
    float var = s2 * (1.f/DM) - mu*mu;
    float rstd = rsqrtf(var + 1e-5f);
    float o0 = (v.x - mu)*rstd*g[c0+0] + b[c0+0];
    float o1 = (v.y - mu)*rstd*g[c0+1] + b[c0+1];
    float o2 = (v.z - mu)*rstd*g[c0+2] + b[c0+2];
    float o3 = (v.w - mu)*rstd*g[c0+3] + b[c0+3];
    uint2 p; p.x = pack2(o0, o1); p.y = pack2(o2, o3);
    *(uint2*)&xbf[(size_t)row*DM + c0] = p;
}

// ---------------- fp32 -> bf16 weight conversion ----------------
__global__ __launch_bounds__(256) void cvt_bf16_kernel(const float* __restrict__ src,
        unsigned short* __restrict__ dst, int n4) {
    int i = blockIdx.x * 256 + threadIdx.x;
    if (i < n4) {
        float4 v = ((const float4*)src)[i];
        uint2 p; p.x = pack2(v.x, v.y); p.y = pack2(v.z, v.w);
        ((uint2*)dst)[i] = p;
    }
}

// ============ QKVG GEMM: 256x256 tile, BK=64, 8-wave, 8-phase counted-vmcnt ============
// A(8192x1024,bf16) x Wcat(6144x1024,bf16)^T. 768 blocks of 512 threads, 128 KiB LDS.
// Round-3 change: ALL fragment loads are inline-asm ds_read_b128. The HIP waitcnt
// pass tracks in-flight global_load_lds (LDS DMA) and inserts conservative vmcnt
// drains before any DS op it cannot prove disjoint -- which defeated the counted
// schedule in rounds 1-2 (MfmaUtil 15%, ~3400cyc/phase vs ~550 of work). With asm
// reads there are no DS MIs visible, so the ONLY waits are ours:
// vmcnt(4) at P4/P8 (never 0 in-loop) + lgkmcnt(0)+sched_barrier(0) per phase.
// Schedule (verified race-free; stage of a region is issued >=1 barrier after its
// last read; vmcnt(4)+barrier guarantees landing before first consume):
//   P1: B(2i+1)h0->Bb1   P2: B(2i+1)h1   P3: B(2i+2)h0->Bb0  P4: B(2i+2)h1, vmcnt(4)
//   P5: A(2i+2)h0->Ab0   P6: A(2i+2)h1   P7: --              P8: A(2i+3)h0+h1->Ab1, vmcnt(4)
// Reads: P1/P5: A[m0-3]+B[n0-1] (12xb128); P2/P6: B[n2-3]; P3/P7: A[m4-7]; P4/P8: none.
// Last iteration's tail stages overrun K into adjacent ws regions (in-bounds, unused).
// Epilogue reuses Ab0 ([64][256] bf16); its __syncthreads drains the tail DMA.
__global__ __launch_bounds__(512, 2) void gemm_qkvg_8ph(
        const unsigned short* __restrict__ A, const unsigned short* __restrict__ W,
        const float* __restrict__ b0, const float* __restrict__ b1,
        const float* __restrict__ b2, const float* __restrict__ b3,
        unsigned short* __restrict__ o0, unsigned short* __restrict__ o1,
        unsigned short* __restrict__ o2, unsigned short* __restrict__ o3) {
    constexpr int KK  = DM;         // 1024
    constexpr int NIT = KK / 128;   // 8 iterations x 2 K-tiles
    __shared__ __align__(16) unsigned short Ab0[16384];
    __shared__ __align__(16) unsigned short Ab1[16384];
    __shared__ __align__(16) unsigned short Bb0[16384];
    __shared__ __align__(16) unsigned short Bb1[16384];

    // XCD-contiguous raster: XCD owns 4 bm x 24 bn; concurrent 32 blocks span
    // 4 bm x 8 bn -> A 2MB + W 4MB working set per XCD L2.
    const int nbn = 6144 >> 8;                 // 24
    const int nb  = (ROWS >> 8) * nbn;         // 768
    const int per = nb >> 3;                   // 96
    int id = blockIdx.x;
    int logical = (id & 7) * per + (id >> 3);
    const int in_grp = 4 * nbn;                // 96
    int g   = logical / in_grp;
    int rem = logical - g * in_grp;
    const int bm = (g * 4 + (rem & 3)) << 8;
    const int bn = (rem >> 2) << 8;

    const int tid  = threadIdx.x;
    const int lane = tid & 63;
    const int wave = tid >> 6;
    const int warp_m = wave >> 2, warp_n = wave & 3;   // 2 x 4 wave grid
    const int fm = lane & 15, kq = lane >> 4;

    // staging map: row = tid>>3 (64 rows/round), 16B block (tid&7) holds global
    // block (tid&7)^(row&7); global_load_lds dest = linear base + tid*16B.
    const int srow = tid >> 3;
    const int scol = ((tid & 7) ^ (srow & 7)) * 8;
    const unsigned short* Asrc = A + (size_t)(bm + srow) * KK + scol;
    const unsigned short* Wsrc = W + (size_t)(bn + srow) * KK + scol;

    int kcol[2];
#pragma unroll
    for (int ks = 0; ks < 2; ks++) kcol[ks] = ((ks*4 + kq) ^ (fm & 7)) * 8;
    const int afm = warp_m * 8192 + fm * 64;
    const int bfm = warp_n * 4096 + fm * 64;

    const unsigned ldsA0 = ldsoff(Ab0), ldsA1 = ldsoff(Ab1);
    const unsigned ldsB0 = ldsoff(Bb0), ldsB1 = ldsoff(Bb1);
    const unsigned aoff0 = (unsigned)((afm + kcol[0]) * 2);
    const unsigned aoff1 = (unsigned)((afm + kcol[1]) * 2);
    const unsigned boff0 = (unsigned)((bfm + kcol[0]) * 2);
    const unsigned boff1 = (unsigned)((bfm + kcol[1]) * 2);

    floatx4 acc[8][4] = {};
    short8 aF[8], bF[8];

// fragment reads: rows are offset:-immediates (2048 B = 1024 shorts per row)
#define RDA(BASE, MI0) do { \
    aF[0]=dsr128<(MI0)*2048  >((BASE)+aoff0); aF[1]=dsr128<(MI0)*2048  >((BASE)+aoff1); \
    aF[2]=dsr128<(MI0+1)*2048>((BASE)+aoff0); aF[3]=dsr128<(MI0+1)*2048>((BASE)+aoff1); \
    aF[4]=dsr128<(MI0+2)*2048>((BASE)+aoff0); aF[5]=dsr128<(MI0+2)*2048>((BASE)+aoff1); \
    aF[6]=dsr128<(MI0+3)*2048>((BASE)+aoff0); aF[7]=dsr128<(MI0+3)*2048>((BASE)+aoff1); \
} while(0)
#define RDB(BASE, NI0) do { \
    bF[(NI0)*2+0]=dsr128<(NI0)*2048  >((BASE)+boff0); bF[(NI0)*2+1]=dsr128<(NI0)*2048  >((BASE)+boff1); \
    bF[(NI0)*2+2]=dsr128<(NI0+1)*2048>((BASE)+boff0); bF[(NI0)*2+3]=dsr128<(NI0+1)*2048>((BASE)+boff1); \
} while(0)

    auto stageHalf = [&](unsigned short* dst, const unsigned short* gsrc) {
        gld_lds16(gsrc,          dst + tid*8);
        gld_lds16(gsrc + 64*KK,  dst + 4096 + tid*8);
    };
    auto mma = [&](int mi0, int ni0) {
        __builtin_amdgcn_s_setprio(1);
#pragma unroll
        for (int mi = 0; mi < 4; mi++)
#pragma unroll
            for (int ni = 0; ni < 2; ni++)
#pragma unroll
                for (int ks = 0; ks < 2; ks++)
                    acc[mi0+mi][ni0+ni] = __builtin_amdgcn_mfma_f32_16x16x32_bf16(
                        aF[mi*2+ks], bF[(ni0+ni)*2+ks], acc[mi0+mi][ni0+ni], 0, 0, 0);
        __builtin_amdgcn_s_setprio(0);
        __builtin_amdgcn_sched_barrier(0);   // keep MFMA cluster inside the phase
    };

    // ---- prologue: A(0),B(0) -> buf0 (8 loads); A(1) -> Ab1 (4 loads) ----
    stageHalf(Ab0,        Asrc);
    stageHalf(Ab0 + 8192, Asrc + 128*KK);
    stageHalf(Bb0,        Wsrc);
    stageHalf(Bb0 + 8192, Wsrc + 128*KK);
    stageHalf(Ab1,        Asrc + 64);
    stageHalf(Ab1 + 8192, Asrc + 128*KK + 64);
    asm volatile("s_waitcnt vmcnt(4)" ::: "memory");   // A0,B0 landed; A1 in flight
    BAR();

#pragma unroll 1
    for (int i = 0; i < NIT; i++) {
        const int kB1 = (2*i + 1) * 64;
        const int kN  = (2*i + 2) * 64;
        // ---- P1 (tile 2i, buf0) ----
        RDA(ldsA0, 0); RDB(ldsB0, 0);
        stageHalf(Bb1, Wsrc + kB1);
        BAR_LG();
        mma(0, 0);
        BAR();
        // ---- P2 ----
        RDB(ldsB0, 2);
        stageHalf(Bb1 + 8192, Wsrc + 128*KK + kB1);
        BAR_LG();
        mma(0, 2);
        BAR();
        // ---- P3 ----
        RDA(ldsA0, 4);
        stageHalf(Bb0, Wsrc + kN);
        BAR_LG();
        mma(4, 0);
        BAR();
        // ---- P4 ----
        stageHalf(Bb0 + 8192, Wsrc + 128*KK + kN);
        BAR_LG();
        mma(4, 2);
        asm volatile("s_waitcnt vmcnt(4)" ::: "memory"); // A(2i+1),B(2i+1) landed
        BAR();
        // ---- P5 (tile 2i+1, buf1) ----
        RDA(ldsA1, 0); RDB(ldsB1, 0);
        stageHalf(Ab0, Asrc + kN);
        BAR_LG();
        mma(0, 0);
        BAR();
        // ---- P6 ----
        RDB(ldsB1, 2);
        stageHalf(Ab0 + 8192, Asrc + 128*KK + kN);
        BAR_LG();
        mma(0, 2);
        BAR();
        // ---- P7 ----
        RDA(ldsA1, 4);
        BAR_LG();
        mma(4, 0);
        BAR();
        // ---- P8 ----
        stageHalf(Ab1,        Asrc + kN + 64);
        stageHalf(Ab1 + 8192, Asrc + 128*KK + kN + 64);
        BAR_LG();
        mma(4, 2);
        asm volatile("s_waitcnt vmcnt(4)" ::: "memory"); // A(2i+2),B(2i+2) landed
        BAR();
    }
#undef RDA
#undef RDB

    // ---- segment routing + epilogue through Ab0 ([64][256] bf16) ----
    int seg = bn >> 10;
    unsigned short* obf; const float* bias; int No, lcb; bool doRope = false; float scale = 1.f;
    if (seg == 0)      { obf = o0; bias = b0; No = 1024; lcb = bn;        doRope = true; }
    else if (seg == 1) { obf = o1; bias = b1; No = 1024; lcb = bn - 1024; doRope = true; scale = 0.125f; }
    else if (seg <= 3) { obf = o2; bias = b2; No = 2048; lcb = bn - 2048; }
    else               { obf = o3; bias = b3; No = 2048; lcb = bn - 4096; }

    const int crow = (lane >> 4) * 4, ccol = lane & 15;
    for (int pass = 0; pass < 4; pass++) {
        if (warp_m == (pass >> 1)) {              // wave-uniform
            int mi0 = (pass & 1) * 4;
#pragma unroll
            for (int mi = 0; mi < 4; mi++) {
#pragma unroll
                for (int ni = 0; ni < 4; ni++) {
                    int tcol = warp_n*64 + ni*16 + ccol;
                    float bcol = bias[lcb + tcol];
#pragma unroll
                    for (int r = 0; r < 4; r++) {
                        int gr = warp_m*128 + (mi0+mi)*16 + crow + r;
                        float v = (acc[mi0+mi][ni][r] + bcol) * scale;
                        if (doRope) {
                            float vp = __shfl_xor(v, 1);   // partner col (tcol^1)
                            int s = (bm + gr) & (SEQ-1);
                            int jj = (tcol & 63) >> 1;
                            float ang = exp2f(-(float)jj * (13.287712379549449f/31.f));
                            float sn, cs;
                            sincosf((float)s * ang, &sn, &cs);
                            v = (tcol & 1) ? (v*cs + vp*sn) : (v*cs - vp*sn);
                        }
                        Ab0[(gr & 63)*256 + tcol] = bfbits(v);
                    }
                }
            }
        }
        __syncthreads();
        {   // 64 rows x 512B; 512 thr x 16B = 16 rows/round, 4 rounds
            int rrow = tid >> 5, rc = (tid & 31) * 8;
#pragma unroll
            for (int it = 0; it < 4; it++) {
                int lr = it*16 + rrow;
                uint4 u = *(const uint4*)&Ab0[lr*256 + rc];
                *(uint4*)&obf[(size_t)(bm + pass*64 + lr)*No + lcb + rc] = u;
            }
        }
        __syncthreads();
    }
}

// ---------------- bf16 MFMA NT GEMM, 128x128 tile, BK=64, XOR-swizzled LDS ----------------
// (retained for the Wo GEMM; QKVG path moved to gemm_qkvg_8ph above)
template<bool QKVG>
__global__ __launch_bounds__(256) void gemm_mfma(
        const unsigned short* __restrict__ A, const unsigned short* __restrict__ W,
        int K, int Ntot,
        const float* __restrict__ b0, const float* __restrict__ b1,
        const float* __restrict__ b2, const float* __restrict__ b3,
        void* __restrict__ o0, void* __restrict__ o1,
        void* __restrict__ o2, void* __restrict__ o3) {
    const int nbn = Ntot >> 7;
    const int nb  = (ROWS >> 7) * nbn;
    const int per = nb >> 3;
    int id = blockIdx.x;
    int logical = (id & 7) * per + (id >> 3);
    const int in_grp = 8 * nbn;
    int g   = logical / in_grp;
    int rem = logical - g * in_grp;
    const int bm = (g * 8 + (rem & 7)) << 7;
    const int bn = (rem >> 3) << 7;

    __shared__ unsigned short smem[16384];     // 32 KB: As[128][64] | Bs[128][64]; epi aliases
    unsigned short* As = smem;
    unsigned short* Bs = smem + 8192;

    const int tid = threadIdx.x;
    const int wave = tid >> 6, lane = tid & 63;
    const int wm = (wave & 1) * 64, wn = (wave >> 1) * 64;

    const int sr = tid >> 3;
    const int scol = (((tid & 7) ^ (sr & 7)) * 8);
    const unsigned short* Ag = A + (size_t)(bm + sr) * K + scol;
    const unsigned short* Wg = W + (size_t)(bn + sr) * K + scol;
    const int fm = lane & 15;
    const int kq = lane >> 4;

    floatx4 acc[4][4] = {};
    for (int k0 = 0; k0 < K; k0 += 64) {
#pragma unroll
        for (int t = 0; t < 4; t++) {
            gld_lds16(Ag + (size_t)(t*32)*K + k0, &As[t*2048 + tid*8]);
            gld_lds16(Wg + (size_t)(t*32)*K + k0, &Bs[t*2048 + tid*8]);
        }
        __syncthreads();
#pragma unroll
        for (int half = 0; half < 2; half++) {
            const int kb = half*4 + kq;
            short8 af[4], bfv[4];
#pragma unroll
            for (int mi = 0; mi < 4; mi++) {
                int r = wm + mi*16 + fm;
                af[mi] = *(const short8*)&As[r*64 + ((kb ^ (r & 7))*8)];
            }
#pragma unroll
            for (int ni = 0; ni < 4; ni++) {
                int r = wn + ni*16 + fm;
                bfv[ni] = *(const short8*)&Bs[r*64 + ((kb ^ (r & 7))*8)];
            }
#pragma unroll
            for (int mi = 0; mi < 4; mi++)
#pragma unroll
                for (int ni = 0; ni < 4; ni++)
                    acc[mi][ni] = __builtin_amdgcn_mfma_f32_16x16x32_bf16(
                                      af[mi], bfv[ni], acc[mi][ni], 0, 0, 0);
        }
        __syncthreads();
    }

    float scale = 1.f; bool doRope = false;
    const float* bias; int No, lcb;
    unsigned short* obf = nullptr; float* of32 = nullptr;
    if (QKVG) {
        int seg = bn >> 10;
        if (seg == 0)      { obf = (unsigned short*)o0; bias = b0; No = 1024; lcb = bn;        doRope = true; }
        else if (seg == 1) { obf = (unsigned short*)o1; bias = b1; No = 1024; lcb = bn - 1024; doRope = true; scale = 0.125f; }
        else if (seg <= 3) { obf = (unsigned short*)o2; bias = b2; No = 2048; lcb = bn - 2048; }
        else               { obf = (unsigned short*)o3; bias = b3; No = 2048; lcb = bn - 4096; }
    } else {
        of32 = (float*)o0; bias = b0; No = Ntot; lcb = bn;
    }

    const int crow = (lane >> 4) * 4, ccol = lane & 15;
    unsigned short* epib = smem;
    float* epif = (float*)smem;
    for (int pass = 0; pass < 2; pass++) {
#pragma unroll
        for (int mi = 0; mi < 4; mi++) {
            if (((wm + mi*16) >> 6) != pass) continue;
#pragma unroll
            for (int ni = 0; ni < 4; ni++) {
                int tcol = wn + ni*16 + ccol;
                float bcol = bias[lcb + tcol];
#pragma unroll
                for (int r = 0; r < 4; r++) {
                    int gr = wm + mi*16 + crow + r;
                    float v = (acc[mi][ni][r] + bcol) * scale;
                    if (QKVG) {
                        if (doRope) {
                            float vp = __shfl_xor(v, 1);
                            int s = (bm + gr) & (SEQ-1);
                            int jj = (tcol & 63) >> 1;
                            float ang = exp2f(-(float)jj * (13.287712379549449f/31.f));
                            float sn, cs;
                            sincosf((float)s * ang, &sn, &cs);
                            v = (tcol & 1) ? (v*cs + vp*sn) : (v*cs - vp*sn);
                        }
                        epib[(gr & 63)*128 + tcol] = bfbits(v);
                    } else {
                        epif[(gr & 63)*128 + tcol] = v;
                    }
                }
            }
        }
        __syncthreads();
        if (QKVG) {
            int rrow = tid >> 4, rc = (tid & 15) * 8;
#pragma unroll
            for (int it = 0; it < 4; it++) {
                int lr = it*16 + rrow;
                uint4 u = *(const uint4*)&epib[lr*128 + rc];
                *(uint4*)&obf[(size_t)(bm + pass*64 + lr)*No + lcb + rc] = u;
            }
        } else {
            int rrow = tid >> 5, rc = (tid & 31) * 4;
#pragma unroll
            for (int it = 0; it < 8; it++) {
                int lr = it*8 + rrow;
                uint4 u = *(const uint4*)&epif[lr*128 + rc];
                *(uint4*)&of32[(size_t)(bm + pass*64 + lr)*No + lcb + rc] = u;
            }
        }
        __syncthreads();
    }
}

// ---------------- retention per-chunk (bf16 in, inner_out in-place bf16, KV fp32) ----------------
__global__ __launch_bounds__(256) void ret_inner_kernel(
        const unsigned short* __restrict__ qry, const unsigned short* __restrict__ key,
        unsigned short* __restrict__ valio, float* __restrict__ kv_out,
        float* __restrict__ iscale_out) {
    int blk = blockIdx.x;
    int c = blk & 63;
    int h = (blk >> 6) & 15;
    int b = blk >> 10;
    float dec = head_decay(h);

    __shared__ float uni[64*65];
    __shared__ float Ks[CL][DK+1];
    __shared__ float Ss[CL][CL+1];
    __shared__ float ascale[CL];
    __shared__ float iscale[CL];

    int tid = threadIdx.x;
    size_t qkbase = ((size_t)(b*SEQ + c*CL))*DM + (size_t)h*DK;
#pragma unroll
    for (int it = 0; it < 2; it++) {
        int s = tid + it*256;
        int i = s >> 3, c0 = (s & 7)*8;
        uint4 uq = *(const uint4*)&qry[qkbase + (size_t)i*DM + c0];
        uint4 uk = *(const uint4*)&key[qkbase + (size_t)i*DM + c0];
        unpack8(uq, &uni[i*65 + c0]);
        unpack8(uk, &Ks[i][c0]);
    }
    if (tid < CL) {
        float ssum = 0.f;
        for (int t = 0; t <= tid; t++) ssum += expf(dec * (float)t);
        ascale[tid] = sqrtf(ssum);
    }
    __syncthreads();

    {
        int tx = tid & 15, ty = tid >> 4;
        float acc[4][4] = {};
        for (int d = 0; d < DK; d++) {
            float av[4], bv[4];
#pragma unroll
            for (int i = 0; i < 4; i++) av[i] = uni[(ty*4+i)*65 + d];
#pragma unroll
            for (int j = 0; j < 4; j++) bv[j] = Ks[tx*4+j][d];
#pragma unroll
            for (int i = 0; i < 4; i++)
#pragma unroll
                for (int j = 0; j < 4; j++)
                    acc[i][j] += av[i]*bv[j];
        }
#pragma unroll
        for (int i = 0; i < 4; i++) {
            int ri = ty*4 + i;
            float ra = 1.f / ascale[ri];
#pragma unroll
            for (int j = 0; j < 4; j++) {
                int cj = tx*4 + j;
                float m = (cj <= ri) ? expf(dec*(float)(ri-cj)) * ra : 0.f;
                Ss[ri][cj] = acc[i][j] * m;
            }
        }
    }
    __syncthreads();
    if (tid < CL) {
        float rs = 0.f;
        for (int j = 0; j < CL; j++) rs += Ss[tid][j];
        float isc = fmaxf(fabsf(rs), 1.f);
        iscale[tid] = isc;
        iscale_out[(size_t)blk*CL + tid] = isc;
    }

    int txv = tid & 15, tyv = tid >> 4;
    int v0 = txv*4, i0 = tyv*4;
    size_t vbase = ((size_t)(b*SEQ + c*CL))*DG + (size_t)h*DV;
    for (int half = 0; half < 2; half++) {
        __syncthreads();
#pragma unroll
        for (int it = 0; it < 2; it++) {
            int s = tid + it*256;
            int i = s >> 3, c0 = (s & 7)*8;
            uint4 uv = *(const uint4*)&valio[vbase + (size_t)i*DG + half*64 + c0];
            unpack8(uv, &uni[i*64 + c0]);
        }
        __syncthreads();
        float acc2[4][4] = {};
        float acc3[4][4] = {};
        for (int j = 0; j < CL; j++) {
            float4 vv = *(const float4*)&uni[j*64 + v0];
            float va[4] = {vv.x, vv.y, vv.z, vv.w};
#pragma unroll
            for (int r = 0; r < 4; r++) {
                float s  = Ss[i0+r][j];
                float kk = Ks[j][i0+r];
#pragma unroll
                for (int q = 0; q < 4; q++) {
                    acc2[r][q] += s*va[q];
                    acc3[r][q] += kk*va[q];
                }
            }
        }
#pragma unroll
        for (int r = 0; r < 4; r++) {
            int i = i0 + r;
            float inv = 1.f / iscale[i];
            uint2 p;
            p.x = pack2(acc2[r][0]*inv, acc2[r][1]*inv);
            p.y = pack2(acc2[r][2]*inv, acc2[r][3]*inv);
            *(uint2*)&valio[vbase + (size_t)i*DG + half*64 + v0] = p;
            float4 kvo = make_float4(acc3[r][0], acc3[r][1], acc3[r][2], acc3[r][3]);
            *(float4*)&kv_out[(size_t)blk*(DK*DV) + (size_t)i*DV + half*64 + v0] = kvo;
        }
    }
}

// ---------------- sequential scan over chunks (in-place KV -> cross_chunk) ----------------
__global__ __launch_bounds__(256) void ret_scan_kernel(float* __restrict__ kv,
        float* __restrict__ cscale_out) {
    int tid = threadIdx.x;
    int col = blockIdx.x*16 + ((tid >> 6) << 2) + (tid & 3);
    int kp  = (tid >> 2) & 15;
    int v   = col & 127;
    int bh  = col >> 7;
    int h   = bh & 15;
    float dec = head_decay(h);
    float cdecay = expf(dec * (float)CL);
    float state[4] = {0.f, 0.f, 0.f, 0.f};
    float scale = 1.f;
    size_t base0 = (size_t)bh*NC*(DK*DV) + (size_t)(kp*4)*DV + v;
    float cur[4];
#pragma unroll
    for (int kk = 0; kk < 4; kk++) cur[kk] = kv[base0 + (size_t)kk*DV];
    for (int c = 0; c < NC; c++) {
        size_t base = base0 + (size_t)c*(DK*DV);
        float nxt[4];
        if (c+1 < NC) {
            size_t nb = base + (size_t)(DK*DV);
#pragma unroll
            for (int kk = 0; kk < 4; kk++) nxt[kk] = kv[nb + (size_t)kk*DV];
        }
        float inv = 1.f / scale;
#pragma unroll
        for (int kk = 0; kk < 4; kk++) kv[base + (size_t)kk*DV] = cur[kk]*inv;
        if (kp == 0) cscale_out[((size_t)bh*NC + c)*DV + v] = scale;
        float ssum = 0.f;
#pragma unroll
        for (int kk = 0; kk < 4; kk++) {
            state[kk] = state[kk]*cdecay + cur[kk];
            ssum += fabsf(state[kk]);
        }
        ssum += __shfl_xor(ssum, 4);
        ssum += __shfl_xor(ssum, 8);
        ssum += __shfl_xor(ssum, 16);
        ssum += __shfl_xor(ssum, 32);
        scale = fmaxf(ssum, 1.f);
        if (c+1 < NC) {
#pragma unroll
            for (int kk = 0; kk < 4; kk++) cur[kk] = nxt[kk];
        }
    }
}

// ---------------- cross_out + combine + groupnorm + silu(gate), in-place bf16 ----------------
__global__ __launch_bounds__(256) void ret_cross_kernel(
        const unsigned short* __restrict__ qry, const float* __restrict__ cross_chunk,
        unsigned short* __restrict__ valio, const float* __restrict__ iscale,
        const float* __restrict__ cscale, const unsigned short* __restrict__ gatebf,
        const float* __restrict__ gn_g, const float* __restrict__ gn_b) {
    int blk = blockIdx.x;
    int c = blk & 63, h = (blk >> 6) & 15, b = blk >> 10;
    float dec = head_decay(h);
    __shared__ float Qs[CL][DK+1];
    __shared__ float CC[DK][DV];
    __shared__ float asc[CL];
    __shared__ float idec[CL];

    int tid = threadIdx.x;
    size_t qbase = ((size_t)(b*SEQ + c*CL))*DM + (size_t)h*DK;
#pragma unroll
    for (int it = 0; it < 2; it++) {
        int s = tid + it*256;
        int i = s >> 3, c0 = (s & 7)*8;
        uint4 uq = *(const uint4*)&qry[qbase + (size_t)i*DM + c0];
        unpack8(uq, &Qs[i][c0]);
    }
    size_t cbase = (size_t)blk * (DK*DV);
#pragma unroll
    for (int t = 0; t < 32; t++) {
        int idx = tid + t*256;
        CC[idx >> 7][idx & 127] = cross_chunk[cbase + idx];
    }
    if (tid < CL) {
        float ssum = 0.f;
        for (int t = 0; t <= tid; t++) ssum += expf(dec * (float)t);
        asc[tid] = sqrtf(ssum);
    }
    __syncthreads();
    if (tid < CL) idec[tid] = expf(dec*(float)(tid+1)) * asc[CL-1] / asc[tid];
    __syncthreads();

    int txv = tid & 31, tyv = tid >> 5;
    int v0 = txv*4, i0 = tyv*8;
    float acc[8][4] = {};
    for (int k = 0; k < DK; k++) {
        float4 cv = *(const float4*)&CC[k][v0];
        float ca[4] = {cv.x, cv.y, cv.z, cv.w};
#pragma unroll
        for (int r = 0; r < 8; r++) {
            float qv = Qs[i0+r][k];
#pragma unroll
            for (int q = 0; q < 4; q++) acc[r][q] += qv*ca[q];
        }
    }
    float4 csv = *(const float4*)&cscale[(size_t)blk*DV + v0];
    float csa[4] = {csv.x, csv.y, csv.z, csv.w};
    float o[8][4];
    float s1[8], s2[8];
#pragma unroll
    for (int r = 0; r < 8; r++) {
        int i = i0 + r;
        float f2 = idec[i] / iscale[(size_t)blk*CL + i];
        size_t orow = ((size_t)(b*SEQ + c*CL + i))*DG + (size_t)h*DV + v0;
        uint2 iu = *(const uint2*)&valio[orow];
        float ioa[4] = { bf2f((unsigned short)(iu.x & 0xffff)),
                         bf2f((unsigned short)(iu.x >> 16)),
                         bf2f((unsigned short)(iu.y & 0xffff)),
                         bf2f((unsigned short)(iu.y >> 16)) };
        float rs1 = 0.f, rs2 = 0.f;
#pragma unroll
        for (int q = 0; q < 4; q++) {
            float ov = ioa[q]/csa[q] + acc[r][q]*f2;
            o[r][q] = ov;
            rs1 += ov; rs2 += ov*ov;
        }
        s1[r] = rs1; s2[r] = rs2;
    }
#pragma unroll
    for (int r = 0; r < 8; r++) {
#pragma unroll
        for (int m = 1; m <= 16; m <<= 1) {
            s1[r] += __shfl_xor(s1[r], m);
            s2[r] += __shfl_xor(s2[r], m);
        }
    }
#pragma unroll
    for (int r = 0; r < 8; r++) {
        int i = i0 + r;
        float mu = s1[r] * (1.f/DV);
        float var = s2[r] * (1.f/DV) - mu*mu;
        float rstd = rsqrtf(var + 1e-5f);
        size_t orow = ((size_t)(b*SEQ + c*CL + i))*DG + (size_t)h*DV + v0;
        uint2 gu = *(const uint2*)&gatebf[orow];
        float ga[4] = { bf2f((unsigned short)(gu.x & 0xffff)),
                        bf2f((unsigned short)(gu.x >> 16)),
                        bf2f((unsigned short)(gu.y & 0xffff)),
                        bf2f((unsigned short)(gu.y >> 16)) };
        float res[4];
#pragma unroll
        for (int q = 0; q < 4; q++) {
            int col = h*DV + v0 + q;
            float xn = (o[r][q] - mu)*rstd*gn_g[col] + gn_b[col];
            float sg = ga[q] / (1.f + expf(-ga[q]));
            res[q] = xn * sg;
        }
        uint2 p; p.x = pack2(res[0], res[1]); p.y = pack2(res[2], res[3]);
        *(uint2*)&valio[orow] = p;
    }
}

extern "C" void kernel_launch(void* const* d_in, const int* in_sizes, int n_in,
                              void* d_out, int out_size, void* d_ws, size_t ws_size,
                              hipStream_t stream) {
    (void)in_sizes; (void)n_in; (void)out_size; (void)ws_size;
    const float* x    = (const float*)d_in[0];
    const float* W_q  = (const float*)d_in[2];
    const float* b_q  = (const float*)d_in[3];
    const float* W_k  = (const float*)d_in[4];
    const float* b_k  = (const float*)d_in[5];
    const float* W_v  = (const float*)d_in[6];
    const float* b_v  = (const float*)d_in[7];
    const float* W_g  = (const float*)d_in[8];
    const float* b_g  = (const float*)d_in[9];
    const float* W_o  = (const float*)d_in[10];
    const float* b_o  = (const float*)d_in[11];
    const float* ln_g = (const float*)d_in[12];
    const float* ln_b = (const float*)d_in[13];
    const float* gn_g = (const float*)d_in[14];
    const float* gn_b = (const float*)d_in[15];
    float* out = (float*)d_out;
    float* ws  = (float*)d_ws;

    // workspace layout (floats) — total ~39.2M floats = 157 MB
    float* keyb   = ws;                       //  4,194,304 (bf16 key 8192x1024)
    float* valb   = keyb   + 4194304;         //  8,388,608 (bf16 val->inner_out->acts 8192x2048)
    float* gateb  = valb   + 8388608;         //  8,388,608 (bf16 gate)
    float* kvbuf  = gateb  + 8388608;         // 16,777,216 fp32 KV->cross_chunk
    float* iscale = kvbuf  + 16777216;        //    131,072
    float* cscale = iscale + 131072;          //    262,144
    float* wobuf  = cscale + 262144;          //  1,048,576 (bf16 W_o 1024x2048)

    unsigned short* xbf  = (unsigned short*)kvbuf;             // 8,388,608 bf16
    unsigned short* Wcat = (unsigned short*)(kvbuf + 4194304); // 6,291,456 bf16 (6144x1024)
    unsigned short* Wo_bf  = (unsigned short*)wobuf;
    unsigned short* key_bf = (unsigned short*)keyb;
    unsigned short* val_bf = (unsigned short*)valb;
    unsigned short* gate_bf= (unsigned short*)gateb;
    unsigned short* qry_bf = (unsigned short*)out;   // d_out doubles as bf16 qry scratch

    ln_cvt_kernel<<<ROWS, 256, 0, stream>>>(x, ln_g, ln_b, xbf);
    cvt_bf16_kernel<<<(DM*DM/4 + 255)/256, 256, 0, stream>>>(W_q, Wcat,             DM*DM/4);
    cvt_bf16_kernel<<<(DM*DM/4 + 255)/256, 256, 0, stream>>>(W_k, Wcat + 1048576,   DM*DM/4);
    cvt_bf16_kernel<<<(DG*DM/4 + 255)/256, 256, 0, stream>>>(W_v, Wcat + 2097152,   DG*DM/4);
    cvt_bf16_kernel<<<(DG*DM/4 + 255)/256, 256, 0, stream>>>(W_g, Wcat + 4194304,   DG*DM/4);
    cvt_bf16_kernel<<<(DM*DG/4 + 255)/256, 256, 0, stream>>>(W_o, Wo_bf,            DM*DG/4);

    // fused QKVG: M=8192, Ntot=6144, K=1024 -> 768 blocks of 512 (8-phase 256^2)
    gemm_qkvg_8ph<<<(ROWS/256)*(6144/256), 512, 0, stream>>>(
        xbf, Wcat, b_q, b_k, b_v, b_g,
        qry_bf, key_bf, val_bf, gate_bf);

    ret_inner_kernel<<<BATCH*NH*NC, 256, 0, stream>>>(qry_bf, key_bf, val_bf, kvbuf, iscale);
    ret_scan_kernel<<<256, 256, 0, stream>>>(kvbuf, cscale);
    ret_cross_kernel<<<BATCH*NH*NC, 256, 0, stream>>>(qry_bf, kvbuf, val_bf, iscale, cscale,
                                                      gate_bf, gn_g, gn_b);

    // Wo: M=8192, N=1024, K=2048 -> 512 blocks, fp32 out
    gemm_mfma<false><<<(ROWS/128)*(DM/128), 256, 0, stream>>>(
        val_bf, Wo_bf, DG, DM, b_o, nullptr, nullptr, nullptr,
        out, nullptr, nullptr, nullptr);
}

// Round 4
// 645.033 us; speedup vs baseline: 1.0196x; 1.0011x over previous
//
#include <hip/hip_runtime.h>
#include <hip/hip_bf16.h>
#include <math.h>

#define BATCH 2
#define SEQ 4096
#define DM 1024
#define NH 16
#define DK 64
#define DV 128
#define NC 64     // number of chunks
#define CL 64     // chunk length
#define ROWS (BATCH*SEQ)   // 8192
#define DG (DM*2)          // 2048 (val/gate width)

typedef __attribute__((ext_vector_type(8))) short short8;
typedef __attribute__((ext_vector_type(4))) float floatx4;

__device__ __forceinline__ float head_decay(int h) {
    return logf(1.0f - exp2f(-5.0f - (float)h));
}
__device__ __forceinline__ unsigned short bfbits(float v) {
    __hip_bfloat16 h = __float2bfloat16(v);
    return *(unsigned short*)&h;
}
__device__ __forceinline__ float bf2f(unsigned short u) {
    unsigned x = ((unsigned)u) << 16;
    return *(float*)&x;
}
__device__ __forceinline__ unsigned pack2(float a, float b) {
    return (unsigned)bfbits(a) | ((unsigned)bfbits(b) << 16);
}
__device__ __forceinline__ void unpack8(uint4 u, float* dst) {
    dst[0]=bf2f((unsigned short)(u.x&0xffff)); dst[1]=bf2f((unsigned short)(u.x>>16));
    dst[2]=bf2f((unsigned short)(u.y&0xffff)); dst[3]=bf2f((unsigned short)(u.y>>16));
    dst[4]=bf2f((unsigned short)(u.z&0xffff)); dst[5]=bf2f((unsigned short)(u.z>>16));
    dst[6]=bf2f((unsigned short)(u.w&0xffff)); dst[7]=bf2f((unsigned short)(u.w>>16));
}
__device__ __forceinline__ void gld_lds16(const unsigned short* g, unsigned short* l) {
    __builtin_amdgcn_global_load_lds(
        (const __attribute__((address_space(1))) unsigned int*)g,
        (__attribute__((address_space(3))) unsigned int*)l, 16, 0, 0);
}
// LDS byte offset of a __shared__ pointer (AS3 pointers are 32-bit offsets)
__device__ __forceinline__ unsigned ldsoff(unsigned short* p) {
    return (unsigned)(unsigned long long)(__attribute__((address_space(3))) unsigned short*)p;
}
// inline-asm ds_read_b128, NO memory clobber: invisible to the waitcnt pass and
// does not force conservative drains. Completion ordering = our manual
// s_waitcnt lgkmcnt(0) + sched_barrier(0) (rule #18).
template<int IMM>
__device__ __forceinline__ short8 dsr128(unsigned addr) {
    short8 r;
    asm volatile("ds_read_b128 %0, %1 offset:%2" : "=v"(r) : "v"(addr), "i"(IMM));
    return r;
}

// ROUND-4 KEY CHANGE: no "memory" clobbers anywhere in the K-loop.
// An asm with a memory clobber is mayLoad/mayStore of ALL memory -> the
// compiler's waitcnt insertion must drain the in-flight LDS-DMA (vmcnt(0))
// before it. Rounds 1-3 executed 2-3 such asms PER PHASE -> full drain per
// phase -> ~3200cyc/phase, MfmaUtil 16%, regardless of all other changes.
// Bare s_barrier builtin + clobber-free waits is exactly the m201 template
// form that measured 1563 TF on this platform.
#define BAR() __builtin_amdgcn_s_barrier()
#define BAR_LG() do { \
    __builtin_amdgcn_s_barrier(); \
    asm volatile("s_waitcnt lgkmcnt(0)"); \
    __builtin_amdgcn_sched_barrier(0); } while(0)
#define WAIT_VM4() do { \
    asm volatile("s_waitcnt vmcnt(4)"); \
    __builtin_amdgcn_sched_barrier(0); } while(0)

// ---------------- LN + cast to bf16: one block per row ----------------
__global__ __launch_bounds__(256) void ln_cvt_kernel(const float* __restrict__ x,
        const float* __restrict__ g, const float* __restrict__ b,
        unsigned short* __restrict__ xbf) {
    int row = blockIdx.x;
    const float* xr = x + (size_t)row * DM;
    int c0 = threadIdx.x * 4;
    float4 v = *(const float4*)&xr[c0];
    float s1 = v.x + v.y + v.z + v.w;
    float s2 = v.x*v.x + v.y*v.y + v.z*v.z + v.w*v.w;
#pragma unroll
    for (int off = 32; off > 0; off >>= 1) {
        s1 += __shfl_down(s1, off);
        s2 += __shfl_down(s2, off);
    }
    __shared__ float a1[4], a2[4];
    int wid = threadIdx.x >> 6;
    if ((threadIdx.x & 63) == 0) { a1[wid] = s1; a2[wid] = s2; }
    __syncthreads();
    s1 = a1[0] + a1[1] + a1[2] + a1[3];
    s2 = a2[0] + a2[1] + a2[2] + a2[3];
    float mu = s1 * (1.f/DM);
    float var = s2 * (1.f/DM) - mu*mu;
    float rstd = rsqrtf(var + 1e-5f);
    float o0 = (v.x - mu)*rstd*g[c0+0] + b[c0+0];
    float o1 = (v.y - mu)*rstd*g[c0+1] + b[c0+1];
    float o2 = (v.z - mu)*rstd*g[c0+2] + b[c0+2];
    float o3 = (v.w - mu)*rstd*g[c0+3] + b[c0+3];
    uint2 p; p.x = pack2(o0, o1); p.y = pack2(o2, o3);
    *(uint2*)&xbf[(size_t)row*DM + c0] = p;
}

// ---------------- fp32 -> bf16 weight conversion ----------------
__global__ __launch_bounds__(256) void cvt_bf16_kernel(const float* __restrict__ src,
        unsigned short* __restrict__ dst, int n4) {
    int i = blockIdx.x * 256 + threadIdx.x;
    if (i < n4) {
        float4 v = ((const float4*)src)[i];
        uint2 p; p.x = pack2(v.x, v.y); p.y = pack2(v.z, v.w);
        ((uint2*)dst)[i] = p;
    }
}

// ============ QKVG GEMM: 256x256 tile, BK=64, 8-wave, 8-phase counted-vmcnt ============
// A(8192x1024,bf16) x Wcat(6144x1024,bf16)^T. 768 blocks of 512 threads, 128 KiB LDS.
// Schedule (race-free; stage of a region issued >=1 barrier after its last read;
// vmcnt(4)+barrier guarantees landing before first consume; vmcnt NEVER 0 in-loop):
//   P1: B(2i+1)h0->Bb1   P2: B(2i+1)h1   P3: B(2i+2)h0->Bb0  P4: B(2i+2)h1, vmcnt(4)
//   P5: A(2i+2)h0->Ab0   P6: A(2i+2)h1   P7: --              P8: A(2i+3)h0+h1->Ab1, vmcnt(4)
// Reads: P1/P5: A[m0-3]+B[n0-1] (12xb128); P2/P6: B[n2-3]; P3/P7: A[m4-7]; P4/P8: none.
// Last iteration's tail stages overrun K into adjacent ws regions (in-bounds, unused).
// Epilogue reuses Ab0 ([64][256] bf16); __syncthreads after the loop drains the
// tail DMA and fences the epilogue's normal LDS stores.
__global__ __launch_bounds__(512, 2) void gemm_qkvg_8ph(
        const unsigned short* __restrict__ A, const unsigned short* __restrict__ W,
        const float* __restrict__ b0, const float* __restrict__ b1,
        const float* __restrict__ b2, const float* __restrict__ b3,
        unsigned short* __restrict__ o0, unsigned short* __restrict__ o1,
        unsigned short* __restrict__ o2, unsigned short* __restrict__ o3) {
    constexpr int KK  = DM;         // 1024
    constexpr int NIT = KK / 128;   // 8 iterations x 2 K-tiles
    __shared__ __align__(16) unsigned short Ab0[16384];
    __shared__ __align__(16) unsigned short Ab1[16384];
    __shared__ __align__(16) unsigned short Bb0[16384];
    __shared__ __align__(16) unsigned short Bb1[16384];

    // XCD-contiguous raster: XCD owns 4 bm x 24 bn groups for L2 reuse.
    const int nbn = 6144 >> 8;                 // 24
    const int nb  = (ROWS >> 8) * nbn;         // 768
    const int per = nb >> 3;                   // 96
    int id = blockIdx.x;
    int logical = (id & 7) * per + (id >> 3);
    const int in_grp = 4 * nbn;                // 96
    int g   = logical / in_grp;
    int rem = logical - g * in_grp;
    const int bm = (g * 4 + (rem & 3)) << 8;
    const int bn = (rem >> 2) << 8;

    const int tid  = threadIdx.x;
    const int lane = tid & 63;
    const int wave = tid >> 6;
    const int warp_m = wave >> 2, warp_n = wave & 3;   // 2 x 4 wave grid
    const int fm = lane & 15, kq = lane >> 4;

    // staging map: row = tid>>3 (64 rows/round), 16B block (tid&7) holds global
    // block (tid&7)^(row&7); global_load_lds dest = linear base + tid*16B.
    const int srow = tid >> 3;
    const int scol = ((tid & 7) ^ (srow & 7)) * 8;
    const unsigned short* Asrc = A + (size_t)(bm + srow) * KK + scol;
    const unsigned short* Wsrc = W + (size_t)(bn + srow) * KK + scol;

    int kcol[2];
#pragma unroll
    for (int ks = 0; ks < 2; ks++) kcol[ks] = ((ks*4 + kq) ^ (fm & 7)) * 8;
    const int afm = warp_m * 8192 + fm * 64;
    const int bfm = warp_n * 4096 + fm * 64;

    const unsigned ldsA0 = ldsoff(Ab0), ldsA1 = ldsoff(Ab1);
    const unsigned ldsB0 = ldsoff(Bb0), ldsB1 = ldsoff(Bb1);
    const unsigned aoff0 = (unsigned)((afm + kcol[0]) * 2);
    const unsigned aoff1 = (unsigned)((afm + kcol[1]) * 2);
    const unsigned boff0 = (unsigned)((bfm + kcol[0]) * 2);
    const unsigned boff1 = (unsigned)((bfm + kcol[1]) * 2);

    floatx4 acc[8][4] = {};
    short8 aF[8], bF[8];

// fragment reads: rows are offset:-immediates (2048 B = 1024 shorts per row)
#define RDA(BASE, MI0) do { \
    aF[0]=dsr128<(MI0)*2048  >((BASE)+aoff0); aF[1]=dsr128<(MI0)*2048  >((BASE)+aoff1); \
    aF[2]=dsr128<(MI0+1)*2048>((BASE)+aoff0); aF[3]=dsr128<(MI0+1)*2048>((BASE)+aoff1); \
    aF[4]=dsr128<(MI0+2)*2048>((BASE)+aoff0); aF[5]=dsr128<(MI0+2)*2048>((BASE)+aoff1); \
    aF[6]=dsr128<(MI0+3)*2048>((BASE)+aoff0); aF[7]=dsr128<(MI0+3)*2048>((BASE)+aoff1); \
} while(0)
#define RDB(BASE, NI0) do { \
    bF[(NI0)*2+0]=dsr128<(NI0)*2048  >((BASE)+boff0); bF[(NI0)*2+1]=dsr128<(NI0)*2048  >((BASE)+boff1); \
    bF[(NI0)*2+2]=dsr128<(NI0+1)*2048>((BASE)+boff0); bF[(NI0)*2+3]=dsr128<(NI0+1)*2048>((BASE)+boff1); \
} while(0)

    auto stageHalf = [&](unsigned short* dst, const unsigned short* gsrc) {
        gld_lds16(gsrc,          dst + tid*8);
        gld_lds16(gsrc + 64*KK,  dst + 4096 + tid*8);
    };
    auto mma = [&](int mi0, int ni0) {
        __builtin_amdgcn_s_setprio(1);
#pragma unroll
        for (int mi = 0; mi < 4; mi++)
#pragma unroll
            for (int ni = 0; ni < 2; ni++)
#pragma unroll
                for (int ks = 0; ks < 2; ks++)
                    acc[mi0+mi][ni0+ni] = __builtin_amdgcn_mfma_f32_16x16x32_bf16(
                        aF[mi*2+ks], bF[(ni0+ni)*2+ks], acc[mi0+mi][ni0+ni], 0, 0, 0);
        __builtin_amdgcn_s_setprio(0);
        __builtin_amdgcn_sched_barrier(0);   // keep MFMA cluster inside the phase
    };

    // ---- prologue: A(0),B(0) -> buf0 (8 loads); A(1) -> Ab1 (4 loads) ----
    stageHalf(Ab0,        Asrc);
    stageHalf(Ab0 + 8192, Asrc + 128*KK);
    stageHalf(Bb0,        Wsrc);
    stageHalf(Bb0 + 8192, Wsrc + 128*KK);
    stageHalf(Ab1,        Asrc + 64);
    stageHalf(Ab1 + 8192, Asrc + 128*KK + 64);
    WAIT_VM4();           // A0,B0 landed; A1 in flight
    BAR();

#pragma unroll 1
    for (int i = 0; i < NIT; i++) {
        const int kB1 = (2*i + 1) * 64;
        const int kN  = (2*i + 2) * 64;
        // ---- P1 (tile 2i, buf0) ----
        RDA(ldsA0, 0); RDB(ldsB0, 0);
        stageHalf(Bb1, Wsrc + kB1);
        BAR_LG();
        mma(0, 0);
        BAR();
        // ---- P2 ----
        RDB(ldsB0, 2);
        stageHalf(Bb1 + 8192, Wsrc + 128*KK + kB1);
        BAR_LG();
        mma(0, 2);
        BAR();
        // ---- P3 ----
        RDA(ldsA0, 4);
        stageHalf(Bb0, Wsrc + kN);
        BAR_LG();
        mma(4, 0);
        BAR();
        // ---- P4 ----
        stageHalf(Bb0 + 8192, Wsrc + 128*KK + kN);
        BAR_LG();
        mma(4, 2);
        WAIT_VM4();       // A(2i+1),B(2i+1) landed
        BAR();
        // ---- P5 (tile 2i+1, buf1) ----
        RDA(ldsA1, 0); RDB(ldsB1, 0);
        stageHalf(Ab0, Asrc + kN);
        BAR_LG();
        mma(0, 0);
        BAR();
        // ---- P6 ----
        RDB(ldsB1, 2);
        stageHalf(Ab0 + 8192, Asrc + 128*KK + kN);
        BAR_LG();
        mma(0, 2);
        BAR();
        // ---- P7 ----
        RDA(ldsA1, 4);
        BAR_LG();
        mma(4, 0);
        BAR();
        // ---- P8 ----
        stageHalf(Ab1,        Asrc + kN + 64);
        stageHalf(Ab1 + 8192, Asrc + 128*KK + kN + 64);
        BAR_LG();
        mma(4, 2);
        WAIT_VM4();       // A(2i+2),B(2i+2) landed
        BAR();
    }
#undef RDA
#undef RDB
    __syncthreads();      // drain tail DMA + fence epilogue's normal LDS stores

    // ---- segment routing + epilogue through Ab0 ([64][256] bf16) ----
    int seg = bn >> 10;
    unsigned short* obf; const float* bias; int No, lcb; bool doRope = false; float scale = 1.f;
    if (seg == 0)      { obf = o0; bias = b0; No = 1024; lcb = bn;        doRope = true; }
    else if (seg == 1) { obf = o1; bias = b1; No = 1024; lcb = bn - 1024; doRope = true; scale = 0.125f; }
    else if (seg <= 3) { obf = o2; bias = b2; No = 2048; lcb = bn - 2048; }
    else               { obf = o3; bias = b3; No = 2048; lcb = bn - 4096; }

    const int crow = (lane >> 4) * 4, ccol = lane & 15;
    for (int pass = 0; pass < 4; pass++) {
        if (warp_m == (pass >> 1)) {              // wave-uniform
            int mi0 = (pass & 1) * 4;
#pragma unroll
            for (int mi = 0; mi < 4; mi++) {
#pragma unroll
                for (int ni = 0; ni < 4; ni++) {
                    int tcol = warp_n*64 + ni*16 + ccol;
                    float bcol = bias[lcb + tcol];
#pragma unroll
                    for (int r = 0; r < 4; r++) {
                        int gr = warp_m*128 + (mi0+mi)*16 + crow + r;
                        float v = (acc[mi0+mi][ni][r] + bcol) * scale;
                        if (doRope) {
                            float vp = __shfl_xor(v, 1);   // partner col (tcol^1)
                            int s = (bm + gr) & (SEQ-1);
                            int jj = (tcol & 63) >> 1;
                            float ang = exp2f(-(float)jj * (13.287712379549449f/31.f));
                            float sn, cs;
                            sincosf((float)s * ang, &sn, &cs);
                            v = (tcol & 1) ? (v*cs + vp*sn) : (v*cs - vp*sn);
                        }
                        Ab0[(gr & 63)*256 + tcol] = bfbits(v);
                    }
                }
            }
        }
        __syncthreads();
        {   // 64 rows x 512B; 512 thr x 16B = 16 rows/round, 4 rounds
            int rrow = tid >> 5, rc = (tid & 31) * 8;
#pragma unroll
            for (int it = 0; it < 4; it++) {
                int lr = it*16 + rrow;
                uint4 u = *(const uint4*)&Ab0[lr*256 + rc];
                *(uint4*)&obf[(size_t)(bm + pass*64 + lr)*No + lcb + rc] = u;
            }
        }
        __syncthreads();
    }
}

// ---------------- bf16 MFMA NT GEMM, 128x128 tile, BK=64, XOR-swizzled LDS ----------------
// (retained for the Wo GEMM; QKVG path moved to gemm_qkvg_8ph above)
template<bool QKVG>
__global__ __launch_bounds__(256) void gemm_mfma(
        const unsigned short* __restrict__ A, const unsigned short* __restrict__ W,
        int K, int Ntot,
        const float* __restrict__ b0, const float* __restrict__ b1,
        const float* __restrict__ b2, const float* __restrict__ b3,
        void* __restrict__ o0, void* __restrict__ o1,
        void* __restrict__ o2, void* __restrict__ o3) {
    const int nbn = Ntot >> 7;
    const int nb  = (ROWS >> 7) * nbn;
    const int per = nb >> 3;
    int id = blockIdx.x;
    int logical = (id & 7) * per + (id >> 3);
    const int in_grp = 8 * nbn;
    int g   = logical / in_grp;
    int rem = logical - g * in_grp;
    const int bm = (g * 8 + (rem & 7)) << 7;
    const int bn = (rem >> 3) << 7;

    __shared__ unsigned short smem[16384];     // 32 KB: As[128][64] | Bs[128][64]; epi aliases
    unsigned short* As = smem;
    unsigned short* Bs = smem + 8192;

    const int tid = threadIdx.x;
    const int wave = tid >> 6, lane = tid & 63;
    const int wm = (wave & 1) * 64, wn = (wave >> 1) * 64;

    const int sr = tid >> 3;
    const int scol = (((tid & 7) ^ (sr & 7)) * 8);
    const unsigned short* Ag = A + (size_t)(bm + sr) * K + scol;
    const unsigned short* Wg = W + (size_t)(bn + sr) * K + scol;
    const int fm = lane & 15;
    const int kq = lane >> 4;

    floatx4 acc[4][4] = {};
    for (int k0 = 0; k0 < K; k0 += 64) {
#pragma unroll
        for (int t = 0; t < 4; t++) {
            gld_lds16(Ag + (size_t)(t*32)*K + k0, &As[t*2048 + tid*8]);
            gld_lds16(Wg + (size_t)(t*32)*K + k0, &Bs[t*2048 + tid*8]);
        }
        __syncthreads();
#pragma unroll
        for (int half = 0; half < 2; half++) {
            const int kb = half*4 + kq;
            short8 af[4], bfv[4];
#pragma unroll
            for (int mi = 0; mi < 4; mi++) {
                int r = wm + mi*16 + fm;
                af[mi] = *(const short8*)&As[r*64 + ((kb ^ (r & 7))*8)];
            }
#pragma unroll
            for (int ni = 0; ni < 4; ni++) {
                int r = wn + ni*16 + fm;
                bfv[ni] = *(const short8*)&Bs[r*64 + ((kb ^ (r & 7))*8)];
            }
#pragma unroll
            for (int mi = 0; mi < 4; mi++)
#pragma unroll
                for (int ni = 0; ni < 4; ni++)
                    acc[mi][ni] = __builtin_amdgcn_mfma_f32_16x16x32_bf16(
                                      af[mi], bfv[ni], acc[mi][ni], 0, 0, 0);
        }
        __syncthreads();
    }

    float scale = 1.f; bool doRope = false;
    const float* bias; int No, lcb;
    unsigned short* obf = nullptr; float* of32 = nullptr;
    if (QKVG) {
        int seg = bn >> 10;
        if (seg == 0)      { obf = (unsigned short*)o0; bias = b0; No = 1024; lcb = bn;        doRope = true; }
        else if (seg == 1) { obf = (unsigned short*)o1; bias = b1; No = 1024; lcb = bn - 1024; doRope = true; scale = 0.125f; }
        else if (seg <= 3) { obf = (unsigned short*)o2; bias = b2; No = 2048; lcb = bn - 2048; }
        else               { obf = (unsigned short*)o3; bias = b3; No = 2048; lcb = bn - 4096; }
    } else {
        of32 = (float*)o0; bias = b0; No = Ntot; lcb = bn;
    }

    const int crow = (lane >> 4) * 4, ccol = lane & 15;
    unsigned short* epib = smem;
    float* epif = (float*)smem;
    for (int pass = 0; pass < 2; pass++) {
#pragma unroll
        for (int mi = 0; mi < 4; mi++) {
            if (((wm + mi*16) >> 6) != pass) continue;
#pragma unroll
            for (int ni = 0; ni < 4; ni++) {
                int tcol = wn + ni*16 + ccol;
                float bcol = bias[lcb + tcol];
#pragma unroll
                for (int r = 0; r < 4; r++) {
                    int gr = wm + mi*16 + crow + r;
                    float v = (acc[mi][ni][r] + bcol) * scale;
                    if (QKVG) {
                        if (doRope) {
                            float vp = __shfl_xor(v, 1);
                            int s = (bm + gr) & (SEQ-1);
                            int jj = (tcol & 63) >> 1;
                            float ang = exp2f(-(float)jj * (13.287712379549449f/31.f));
                            float sn, cs;
                            sincosf((float)s * ang, &sn, &cs);
                            v = (tcol & 1) ? (v*cs + vp*sn) : (v*cs - vp*sn);
                        }
                        epib[(gr & 63)*128 + tcol] = bfbits(v);
                    } else {
                        epif[(gr & 63)*128 + tcol] = v;
                    }
                }
            }
        }
        __syncthreads();
        if (QKVG) {
            int rrow = tid >> 4, rc = (tid & 15) * 8;
#pragma unroll
            for (int it = 0; it < 4; it++) {
                int lr = it*16 + rrow;
                uint4 u = *(const uint4*)&epib[lr*128 + rc];
                *(uint4*)&obf[(size_t)(bm + pass*64 + lr)*No + lcb + rc] = u;
            }
        } else {
            int rrow = tid >> 5, rc = (tid & 31) * 4;
#pragma unroll
            for (int it = 0; it < 8; it++) {
                int lr = it*8 + rrow;
                uint4 u = *(const uint4*)&epif[lr*128 + rc];
                *(uint4*)&of32[(size_t)(bm + pass*64 + lr)*No + lcb + rc] = u;
            }
        }
        __syncthreads();
    }
}

// ---------------- retention per-chunk (bf16 in, inner_out in-place bf16, KV fp32) ----------------
__global__ __launch_bounds__(256) void ret_inner_kernel(
        const unsigned short* __restrict__ qry, const unsigned short* __restrict__ key,
        unsigned short* __restrict__ valio, float* __restrict__ kv_out,
        float* __restrict__ iscale_out) {
    int blk = blockIdx.x;
    int c = blk & 63;
    int h = (blk >> 6) & 15;
    int b = blk >> 10;
    float dec = head_decay(h);

    __shared__ float uni[64*65];
    __shared__ float Ks[CL][DK+1];
    __shared__ float Ss[CL][CL+1];
    __shared__ float ascale[CL];
    __shared__ float iscale[CL];

    int tid = threadIdx.x;
    size_t qkbase = ((size_t)(b*SEQ + c*CL))*DM + (size_t)h*DK;
#pragma unroll
    for (int it = 0; it < 2; it++) {
        int s = tid + it*256;
        int i = s >> 3, c0 = (s & 7)*8;
        uint4 uq = *(const uint4*)&qry[qkbase + (size_t)i*DM + c0];
        uint4 uk = *(const uint4*)&key[qkbase + (size_t)i*DM + c0];
        unpack8(uq, &uni[i*65 + c0]);
        unpack8(uk, &Ks[i][c0]);
    }
    if (tid < CL) {
        float ssum = 0.f;
        for (int t = 0; t <= tid; t++) ssum += expf(dec * (float)t);
        ascale[tid] = sqrtf(ssum);
    }
    __syncthreads();

    {
        int tx = tid & 15, ty = tid >> 4;
        float acc[4][4] = {};
        for (int d = 0; d < DK; d++) {
            float av[4], bv[4];
#pragma unroll
            for (int i = 0; i < 4; i++) av[i] = uni[(ty*4+i)*65 + d];
#pragma unroll
            for (int j = 0; j < 4; j++) bv[j] = Ks[tx*4+j][d];
#pragma unroll
            for (int i = 0; i < 4; i++)
#pragma unroll
                for (int j = 0; j < 4; j++)
                    acc[i][j] += av[i]*bv[j];
        }
#pragma unroll
        for (int i = 0; i < 4; i++) {
            int ri = ty*4 + i;
            float ra = 1.f / ascale[ri];
#pragma unroll
            for (int j = 0; j < 4; j++) {
                int cj = tx*4 + j;
                float m = (cj <= ri) ? expf(dec*(float)(ri-cj)) * ra : 0.f;
                Ss[ri][cj] = acc[i][j] * m;
            }
        }
    }
    __syncthreads();
    if (tid < CL) {
        float rs = 0.f;
        for (int j = 0; j < CL; j++) rs += Ss[tid][j];
        float isc = fmaxf(fabsf(rs), 1.f);
        iscale[tid] = isc;
        iscale_out[(size_t)blk*CL + tid] = isc;
    }

    int txv = tid & 15, tyv = tid >> 4;
    int v0 = txv*4, i0 = tyv*4;
    size_t vbase = ((size_t)(b*SEQ + c*CL))*DG + (size_t)h*DV;
    for (int half = 0; half < 2; half++) {
        __syncthreads();
#pragma unroll
        for (int it = 0; it < 2; it++) {
            int s = tid + it*256;
            int i = s >> 3, c0 = (s & 7)*8;
            uint4 uv = *(const uint4*)&valio[vbase + (size_t)i*DG + half*64 + c0];
            unpack8(uv, &uni[i*64 + c0]);
        }
        __syncthreads();
        float acc2[4][4] = {};
        float acc3[4][4] = {};
        for (int j = 0; j < CL; j++) {
            float4 vv = *(const float4*)&uni[j*64 + v0];
            float va[4] = {vv.x, vv.y, vv.z, vv.w};
#pragma unroll
            for (int r = 0; r < 4; r++) {
                float s  = Ss[i0+r][j];
                float kk = Ks[j][i0+r];
#pragma unroll
                for (int q = 0; q < 4; q++) {
                    acc2[r][q] += s*va[q];
                    acc3[r][q] += kk*va[q];
                }
            }
        }
#pragma unroll
        for (int r = 0; r < 4; r++) {
            int i = i0 + r;
            float inv = 1.f / iscale[i];
            uint2 p;
            p.x = pack2(acc2[r][0]*inv, acc2[r][1]*inv);
            p.y = pack2(acc2[r][2]*inv, acc2[r][3]*inv);
            *(uint2*)&valio[vbase + (size_t)i*DG + half*64 + v0] = p;
            float4 kvo = make_float4(acc3[r][0], acc3[r][1], acc3[r][2], acc3[r][3]);
            *(float4*)&kv_out[(size_t)blk*(DK*DV) + (size_t)i*DV + half*64 + v0] = kvo;
        }
    }
}

// ---------------- sequential scan over chunks (in-place KV -> cross_chunk) ----------------
__global__ __launch_bounds__(256) void ret_scan_kernel(float* __restrict__ kv,
        float* __restrict__ cscale_out) {
    int tid = threadIdx.x;
    int col = blockIdx.x*16 + ((tid >> 6) << 2) + (tid & 3);
    int kp  = (tid >> 2) & 15;
    int v   = col & 127;
    int bh  = col >> 7;
    int h   = bh & 15;
    float dec = head_decay(h);
    float cdecay = expf(dec * (float)CL);
    float state[4] = {0.f, 0.f, 0.f, 0.f};
    float scale = 1.f;
    size_t base0 = (size_t)bh*NC*(DK*DV) + (size_t)(kp*4)*DV + v;
    float cur[4];
#pragma unroll
    for (int kk = 0; kk < 4; kk++) cur[kk] = kv[base0 + (size_t)kk*DV];
    for (int c = 0; c < NC; c++) {
        size_t base = base0 + (size_t)c*(DK*DV);
        float nxt[4];
        if (c+1 < NC) {
            size_t nb = base + (size_t)(DK*DV);
#pragma unroll
            for (int kk = 0; kk < 4; kk++) nxt[kk] = kv[nb + (size_t)kk*DV];
        }
        float inv = 1.f / scale;
#pragma unroll
        for (int kk = 0; kk < 4; kk++) kv[base + (size_t)kk*DV] = cur[kk]*inv;
        if (kp == 0) cscale_out[((size_t)bh*NC + c)*DV + v] = scale;
        float ssum = 0.f;
#pragma unroll
        for (int kk = 0; kk < 4; kk++) {
            state[kk] = state[kk]*cdecay + cur[kk];
            ssum += fabsf(state[kk]);
        }
        ssum += __shfl_xor(ssum, 4);
        ssum += __shfl_xor(ssum, 8);
        ssum += __shfl_xor(ssum, 16);
        ssum += __shfl_xor(ssum, 32);
        scale = fmaxf(ssum, 1.f);
        if (c+1 < NC) {
#pragma unroll
            for (int kk = 0; kk < 4; kk++) cur[kk] = nxt[kk];
        }
    }
}

// ---------------- cross_out + combine + groupnorm + silu(gate), in-place bf16 ----------------
__global__ __launch_bounds__(256) void ret_cross_kernel(
        const unsigned short* __restrict__ qry, const float* __restrict__ cross_chunk,
        unsigned short* __restrict__ valio, const float* __restrict__ iscale,
        const float* __restrict__ cscale, const unsigned short* __restrict__ gatebf,
        const float* __restrict__ gn_g, const float* __restrict__ gn_b) {
    int blk = blockIdx.x;
    int c = blk & 63, h = (blk >> 6) & 15, b = blk >> 10;
    float dec = head_decay(h);
    __shared__ float Qs[CL][DK+1];
    __shared__ float CC[DK][DV];
    __shared__ float asc[CL];
    __shared__ float idec[CL];

    int tid = threadIdx.x;
    size_t qbase = ((size_t)(b*SEQ + c*CL))*DM + (size_t)h*DK;
#pragma unroll
    for (int it = 0; it < 2; it++) {
        int s = tid + it*256;
        int i = s >> 3, c0 = (s & 7)*8;
        uint4 uq = *(const uint4*)&qry[qbase + (size_t)i*DM + c0];
        unpack8(uq, &Qs[i][c0]);
    }
    size_t cbase = (size_t)blk * (DK*DV);
#pragma unroll
    for (int t = 0; t < 32; t++) {
        int idx = tid + t*256;
        CC[idx >> 7][idx & 127] = cross_chunk[cbase + idx];
    }
    if (tid < CL) {
        float ssum = 0.f;
        for (int t = 0; t <= tid; t++) ssum += expf(dec * (float)t);
        asc[tid] = sqrtf(ssum);
    }
    __syncthreads();
    if (tid < CL) idec[tid] = expf(dec*(float)(tid+1)) * asc[CL-1] / asc[tid];
    __syncthreads();

    int txv = tid & 31, tyv = tid >> 5;
    int v0 = txv*4, i0 = tyv*8;
    float acc[8][4] = {};
    for (int k = 0; k < DK; k++) {
        float4 cv = *(const float4*)&CC[k][v0];
        float ca[4] = {cv.x, cv.y, cv.z, cv.w};
#pragma unroll
        for (int r = 0; r < 8; r++) {
            float qv = Qs[i0+r][k];
#pragma unroll
            for (int q = 0; q < 4; q++) acc[r][q] += qv*ca[q];
        }
    }
    float4 csv = *(const float4*)&cscale[(size_t)blk*DV + v0];
    float csa[4] = {csv.x, csv.y, csv.z, csv.w};
    float o[8][4];
    float s1[8], s2[8];
#pragma unroll
    for (int r = 0; r < 8; r++) {
        int i = i0 + r;
        float f2 = idec[i] / iscale[(size_t)blk*CL + i];
        size_t orow = ((size_t)(b*SEQ + c*CL + i))*DG + (size_t)h*DV + v0;
        uint2 iu = *(const uint2*)&valio[orow];
        float ioa[4] = { bf2f((unsigned short)(iu.x & 0xffff)),
                         bf2f((unsigned short)(iu.x >> 16)),
                         bf2f((unsigned short)(iu.y & 0xffff)),
                         bf2f((unsigned short)(iu.y >> 16)) };
        float rs1 = 0.f, rs2 = 0.f;
#pragma unroll
        for (int q = 0; q < 4; q++) {
            float ov = ioa[q]/csa[q] + acc[r][q]*f2;
            o[r][q] = ov;
            rs1 += ov; rs2 += ov*ov;
        }
        s1[r] = rs1; s2[r] = rs2;
    }
#pragma unroll
    for (int r = 0; r < 8; r++) {
#pragma unroll
        for (int m = 1; m <= 16; m <<= 1) {
            s1[r] += __shfl_xor(s1[r], m);
            s2[r] += __shfl_xor(s2[r], m);
        }
    }
#pragma unroll
    for (int r = 0; r < 8; r++) {
        int i = i0 + r;
        float mu = s1[r] * (1.f/DV);
        float var = s2[r] * (1.f/DV) - mu*mu;
        float rstd = rsqrtf(var + 1e-5f);
        size_t orow = ((size_t)(b*SEQ + c*CL + i))*DG + (size_t)h*DV + v0;
        uint2 gu = *(const uint2*)&gatebf[orow];
        float ga[4] = { bf2f((unsigned short)(gu.x & 0xffff)),
                        bf2f((unsigned short)(gu.x >> 16)),
                        bf2f((unsigned short)(gu.y & 0xffff)),
                        bf2f((unsigned short)(gu.y >> 16)) };
        float res[4];
#pragma unroll
        for (int q = 0; q < 4; q++) {
            int col = h*DV + v0 + q;
            float xn = (o[r][q] - mu)*rstd*gn_g[col] + gn_b[col];
            float sg = ga[q] / (1.f + expf(-ga[q]));
            res[q] = xn * sg;
        }
        uint2 p; p.x = pack2(res[0], res[1]); p.y = pack2(res[2], res[3]);
        *(uint2*)&valio[orow] = p;
    }
}

extern "C" void kernel_launch(void* const* d_in, const int* in_sizes, int n_in,
                              void* d_out, int out_size, void* d_ws, size_t ws_size,
                              hipStream_t stream) {
    (void)in_sizes; (void)n_in; (void)out_size; (void)ws_size;
    const float* x    = (const float*)d_in[0];
    const float* W_q  = (const float*)d_in[2];
    const float* b_q  = (const float*)d_in[3];
    const float* W_k  = (const float*)d_in[4];
    const float* b_k  = (const float*)d_in[5];
    const float* W_v  = (const float*)d_in[6];
    const float* b_v  = (const float*)d_in[7];
    const float* W_g  = (const float*)d_in[8];
    const float* b_g  = (const float*)d_in[9];
    const float* W_o  = (const float*)d_in[10];
    const float* b_o  = (const float*)d_in[11];
    const float* ln_g = (const float*)d_in[12];
    const float* ln_b = (const float*)d_in[13];
    const float* gn_g = (const float*)d_in[14];
    const float* gn_b = (const float*)d_in[15];
    float* out = (float*)d_out;
    float* ws  = (float*)d_ws;

    // workspace layout (floats) — total ~39.2M floats = 157 MB
    float* keyb   = ws;                       //  4,194,304 (bf16 key 8192x1024)
    float* valb   = keyb   + 4194304;         //  8,388,608 (bf16 val->inner_out->acts 8192x2048)
    float* gateb  = valb   + 8388608;         //  8,388,608 (bf16 gate)
    float* kvbuf  = gateb  + 8388608;         // 16,777,216 fp32 KV->cross_chunk
    float* iscale = kvbuf  + 16777216;        //    131,072
    float* cscale = iscale + 131072;          //    262,144
    float* wobuf  = cscale + 262144;          //  1,048,576 (bf16 W_o 1024x2048)

    unsigned short* xbf  = (unsigned short*)kvbuf;             // 8,388,608 bf16
    unsigned short* Wcat = (unsigned short*)(kvbuf + 4194304); // 6,291,456 bf16 (6144x1024)
    unsigned short* Wo_bf  = (unsigned short*)wobuf;
    unsigned short* key_bf = (unsigned short*)keyb;
    unsigned short* val_bf = (unsigned short*)valb;
    unsigned short* gate_bf= (unsigned short*)gateb;
    unsigned short* qry_bf = (unsigned short*)out;   // d_out doubles as bf16 qry scratch

    ln_cvt_kernel<<<ROWS, 256, 0, stream>>>(x, ln_g, ln_b, xbf);
    cvt_bf16_kernel<<<(DM*DM/4 + 255)/256, 256, 0, stream>>>(W_q, Wcat,             DM*DM/4);
    cvt_bf16_kernel<<<(DM*DM/4 + 255)/256, 256, 0, stream>>>(W_k, Wcat + 1048576,   DM*DM/4);
    cvt_bf16_kernel<<<(DG*DM/4 + 255)/256, 256, 0, stream>>>(W_v, Wcat + 2097152,   DG*DM/4);
    cvt_bf16_kernel<<<(DG*DM/4 + 255)/256, 256, 0, stream>>>(W_g, Wcat + 4194304,   DG*DM/4);
    cvt_bf16_kernel<<<(DM*DG/4 + 255)/256, 256, 0, stream>>>(W_o, Wo_bf,            DM*DG/4);

    // fused QKVG: M=8192, Ntot=6144, K=1024 -> 768 blocks of 512 (8-phase 256^2)
    gemm_qkvg_8ph<<<(ROWS/256)*(6144/256), 512, 0, stream>>>(
        xbf, Wcat, b_q, b_k, b_v, b_g,
        qry_bf, key_bf, val_bf, gate_bf);

    ret_inner_kernel<<<BATCH*NH*NC, 256, 0, stream>>>(qry_bf, key_bf, val_bf, kvbuf, iscale);
    ret_scan_kernel<<<256, 256, 0, stream>>>(kvbuf, cscale);
    ret_cross_kernel<<<BATCH*NH*NC, 256, 0, stream>>>(qry_bf, kvbuf, val_bf, iscale, cscale,
                                                      gate_bf, gn_g, gn_b);

    // Wo: M=8192, N=1024, K=2048 -> 512 blocks, fp32 out
    gemm_mfma<false><<<(ROWS/128)*(DM/128), 256, 0, stream>>>(
        val_bf, Wo_bf, DG, DM, b_o, nullptr, nullptr, nullptr,
        out, nullptr, nullptr, nullptr);
}

// Round 5
// 577.651 us; speedup vs baseline: 1.1385x; 1.1166x over previous
//
#include <hip/hip_runtime.h>
#include <hip/hip_bf16.h>
#include <math.h>

#define BATCH 2
#define SEQ 4096
#define DM 1024
#define NH 16
#define DK 64
#define DV 128
#define NC 64     // number of chunks
#define CL 64     // chunk length
#define ROWS (BATCH*SEQ)   // 8192
#define DG (DM*2)          // 2048 (val/gate width)

typedef __attribute__((ext_vector_type(8))) short short8;
typedef __attribute__((ext_vector_type(4))) float floatx4;

__device__ __forceinline__ float head_decay(int h) {
    return logf(1.0f - exp2f(-5.0f - (float)h));
}
__device__ __forceinline__ unsigned short bfbits(float v) {
    __hip_bfloat16 h = __float2bfloat16(v);
    return *(unsigned short*)&h;
}
__device__ __forceinline__ float bf2f(unsigned short u) {
    unsigned x = ((unsigned)u) << 16;
    return *(float*)&x;
}
__device__ __forceinline__ unsigned pack2(float a, float b) {
    return (unsigned)bfbits(a) | ((unsigned)bfbits(b) << 16);
}
__device__ __forceinline__ void unpack8(uint4 u, float* dst) {
    dst[0]=bf2f((unsigned short)(u.x&0xffff)); dst[1]=bf2f((unsigned short)(u.x>>16));
    dst[2]=bf2f((unsigned short)(u.y&0xffff)); dst[3]=bf2f((unsigned short)(u.y>>16));
    dst[4]=bf2f((unsigned short)(u.z&0xffff)); dst[5]=bf2f((unsigned short)(u.z>>16));
    dst[6]=bf2f((unsigned short)(u.w&0xffff)); dst[7]=bf2f((unsigned short)(u.w>>16));
}
__device__ __forceinline__ void gld_lds16(const unsigned short* g, unsigned short* l) {
    __builtin_amdgcn_global_load_lds(
        (const __attribute__((address_space(1))) unsigned int*)g,
        (__attribute__((address_space(3))) unsigned int*)l, 16, 0, 0);
}

// ---------------- LN + cast to bf16: one WAVE per row (shuffle-only) ----------------
__global__ __launch_bounds__(256) void ln_cvt_kernel(const float* __restrict__ x,
        const float* __restrict__ g, const float* __restrict__ b,
        unsigned short* __restrict__ xbf) {
    int row  = blockIdx.x * 4 + (threadIdx.x >> 6);
    int lane = threadIdx.x & 63;
    const float* xr = x + (size_t)row * DM;
    int c0 = lane * 16;
    float4 v[4];
#pragma unroll
    for (int t = 0; t < 4; t++) v[t] = *(const float4*)&xr[c0 + t*4];
    float s1 = 0.f, s2 = 0.f;
#pragma unroll
    for (int t = 0; t < 4; t++) {
        s1 += v[t].x + v[t].y + v[t].z + v[t].w;
        s2 += v[t].x*v[t].x + v[t].y*v[t].y + v[t].z*v[t].z + v[t].w*v[t].w;
    }
#pragma unroll
    for (int off = 32; off > 0; off >>= 1) {
        s1 += __shfl_down(s1, off);
        s2 += __shfl_down(s2, off);
    }
    s1 = __shfl(s1, 0);
    s2 = __shfl(s2, 0);
    float mu   = s1 * (1.f/DM);
    float var  = s2 * (1.f/DM) - mu*mu;
    float rstd = rsqrtf(var + 1e-5f);
    uint4 o[2];
    unsigned* ow = (unsigned*)o;
#pragma unroll
    for (int t = 0; t < 4; t++) {
        float4 gv = *(const float4*)&g[c0 + t*4];
        float4 bv = *(const float4*)&b[c0 + t*4];
        float e0 = (v[t].x - mu)*rstd*gv.x + bv.x;
        float e1 = (v[t].y - mu)*rstd*gv.y + bv.y;
        float e2 = (v[t].z - mu)*rstd*gv.z + bv.z;
        float e3 = (v[t].w - mu)*rstd*gv.w + bv.w;
        ow[t*2+0] = pack2(e0, e1);
        ow[t*2+1] = pack2(e2, e3);
    }
    uint4* dst = (uint4*)&xbf[(size_t)row*DM + c0];
    dst[0] = o[0];
    dst[1] = o[1];
}

// ---------------- fp32 -> bf16 weight conversion ----------------
__global__ __launch_bounds__(256) void cvt_bf16_kernel(const float* __restrict__ src,
        unsigned short* __restrict__ dst, int n4) {
    int i = blockIdx.x * 256 + threadIdx.x;
    if (i < n4) {
        float4 v = ((const float4*)src)[i];
        uint2 p; p.x = pack2(v.x, v.y); p.y = pack2(v.z, v.w);
        ((uint2*)dst)[i] = p;
    }
}

// ---------------- bf16 MFMA NT GEMM, 128x128 tile, BK=64, XOR-swizzled LDS ----------------
// Round-5: __launch_bounds__(256, 3) — declare 3 waves/EU (== 3 blocks/CU for
// 256-thr blocks, guide §1). Rounds 0-4 all measured OccupancyPercent ~23%
// (8 waves/CU = 2 blocks/CU) while the m97 reference structure runs 12 waves/CU
// (37%) at 874-912 TF: its mechanism is TLP across co-resident blocks hiding the
// barrier drain (m114), not intra-block pipelining. Our 92 VGPR + 64 AGPR = 156
// fits 3/SIMD but the allocator never targeted it; this pins the budget.
// Staging: thread tid stages row r=tid>>3, col-block q=tid&7 -> global col-block
// q^(r&7); fragment ds_read_b128 then 2-way conflict (free). 32 MFMA per barrier.
// Epilogue tile aliases As/Bs -> LDS stays 32 KB (5 blocks/CU by LDS).
// QKVG=true: A(8192x1024) x Wcat(6144x1024)^T; per-segment epilogue
//   seg0 Q(rope) seg1 K(rope, x.125) seg2,3 V seg4,5 G (all bf16 out).
// QKVG=false: A x W^T + b0 -> o0 (fp32). XCD-aware 1D raster.
template<bool QKVG>
__global__ __launch_bounds__(256, 3) void gemm_mfma(
        const unsigned short* __restrict__ A, const unsigned short* __restrict__ W,
        int K, int Ntot,
        const float* __restrict__ b0, const float* __restrict__ b1,
        const float* __restrict__ b2, const float* __restrict__ b3,
        void* __restrict__ o0, void* __restrict__ o1,
        void* __restrict__ o2, void* __restrict__ o3) {
    const int nbn = Ntot >> 7;
    const int nb  = (ROWS >> 7) * nbn;
    const int per = nb >> 3;
    int id = blockIdx.x;
    int logical = (id & 7) * per + (id >> 3);
    const int in_grp = 8 * nbn;
    int g   = logical / in_grp;
    int rem = logical - g * in_grp;
    const int bm = (g * 8 + (rem & 7)) << 7;
    const int bn = (rem >> 3) << 7;

    __shared__ unsigned short smem[16384];     // 32 KB: As[128][64] | Bs[128][64]; epi aliases
    unsigned short* As = smem;
    unsigned short* Bs = smem + 8192;

    const int tid = threadIdx.x;
    const int wave = tid >> 6, lane = tid & 63;
    const int wm = (wave & 1) * 64, wn = (wave >> 1) * 64;

    const int sr = tid >> 3;
    const int scol = (((tid & 7) ^ (sr & 7)) * 8);
    const unsigned short* Ag = A + (size_t)(bm + sr) * K + scol;
    const unsigned short* Wg = W + (size_t)(bn + sr) * K + scol;
    const int fm = lane & 15;
    const int kq = lane >> 4;

    floatx4 acc[4][4] = {};
    for (int k0 = 0; k0 < K; k0 += 64) {
#pragma unroll
        for (int t = 0; t < 4; t++) {
            gld_lds16(Ag + (size_t)(t*32)*K + k0, &As[t*2048 + tid*8]);
            gld_lds16(Wg + (size_t)(t*32)*K + k0, &Bs[t*2048 + tid*8]);
        }
        __syncthreads();
#pragma unroll
        for (int half = 0; half < 2; half++) {
            const int kb = half*4 + kq;        // k-block 0..7
            short8 af[4], bfv[4];
#pragma unroll
            for (int mi = 0; mi < 4; mi++) {
                int r = wm + mi*16 + fm;
                af[mi] = *(const short8*)&As[r*64 + ((kb ^ (r & 7))*8)];
            }
#pragma unroll
            for (int ni = 0; ni < 4; ni++) {
                int r = wn + ni*16 + fm;
                bfv[ni] = *(const short8*)&Bs[r*64 + ((kb ^ (r & 7))*8)];
            }
#pragma unroll
            for (int mi = 0; mi < 4; mi++)
#pragma unroll
                for (int ni = 0; ni < 4; ni++)
                    acc[mi][ni] = __builtin_amdgcn_mfma_f32_16x16x32_bf16(
                                      af[mi], bfv[ni], acc[mi][ni], 0, 0, 0);
        }
        __syncthreads();
    }

    // segment routing (block-uniform)
    float scale = 1.f; bool doRope = false;
    const float* bias; int No, lcb;
    unsigned short* obf = nullptr; float* of32 = nullptr;
    if (QKVG) {
        int seg = bn >> 10;
        if (seg == 0)      { obf = (unsigned short*)o0; bias = b0; No = 1024; lcb = bn;        doRope = true; }
        else if (seg == 1) { obf = (unsigned short*)o1; bias = b1; No = 1024; lcb = bn - 1024; doRope = true; scale = 0.125f; }
        else if (seg <= 3) { obf = (unsigned short*)o2; bias = b2; No = 2048; lcb = bn - 2048; }
        else               { obf = (unsigned short*)o3; bias = b3; No = 2048; lcb = bn - 4096; }
    } else {
        of32 = (float*)o0; bias = b0; No = Ntot; lcb = bn;
    }

    // epilogue through LDS (aliases As/Bs, safe after final in-loop barrier)
    const int crow = (lane >> 4) * 4, ccol = lane & 15;
    unsigned short* epib = smem;
    float* epif = (float*)smem;
    for (int pass = 0; pass < 2; pass++) {
#pragma unroll
        for (int mi = 0; mi < 4; mi++) {
            if (((wm + mi*16) >> 6) != pass) continue;   // wave-uniform
#pragma unroll
            for (int ni = 0; ni < 4; ni++) {
                int tcol = wn + ni*16 + ccol;
                float bcol = bias[lcb + tcol];
#pragma unroll
                for (int r = 0; r < 4; r++) {
                    int gr = wm + mi*16 + crow + r;
                    float v = (acc[mi][ni][r] + bcol) * scale;
                    if (QKVG) {
                        if (doRope) {
                            float vp = __shfl_xor(v, 1);   // partner col (tcol^1), same row
                            int s = (bm + gr) & (SEQ-1);
                            int jj = (tcol & 63) >> 1;
                            float ang = exp2f(-(float)jj * (13.287712379549449f/31.f));
                            float sn, cs;
                            sincosf((float)s * ang, &sn, &cs);
                            v = (tcol & 1) ? (v*cs + vp*sn) : (v*cs - vp*sn);
                        }
                        epib[(gr & 63)*128 + tcol] = bfbits(v);
                    } else {
                        epif[(gr & 63)*128 + tcol] = v;
                    }
                }
            }
        }
        __syncthreads();
        if (QKVG) {       // 16 thr/row x 16B => 256B rows; 16 rows/iter, 4 iters
            int rrow = tid >> 4, rc = (tid & 15) * 8;
#pragma unroll
            for (int it = 0; it < 4; it++) {
                int lr = it*16 + rrow;
                uint4 u = *(const uint4*)&epib[lr*128 + rc];
                *(uint4*)&obf[(size_t)(bm + pass*64 + lr)*No + lcb + rc] = u;
            }
        } else {          // 32 thr/row x 16B => 512B rows; 8 rows/iter, 8 iters
            int rrow = tid >> 5, rc = (tid & 31) * 4;
#pragma unroll
            for (int it = 0; it < 8; it++) {
                int lr = it*8 + rrow;
                uint4 u = *(const uint4*)&epif[lr*128 + rc];
                *(uint4*)&of32[(size_t)(bm + pass*64 + lr)*No + lcb + rc] = u;
            }
        }
        __syncthreads();
    }
}

// ---------------- retention per-chunk (bf16 in, inner_out in-place bf16, KV fp32) ----------------
__global__ __launch_bounds__(256) void ret_inner_kernel(
        const unsigned short* __restrict__ qry, const unsigned short* __restrict__ key,
        unsigned short* __restrict__ valio, float* __restrict__ kv_out,
        float* __restrict__ iscale_out) {
    int blk = blockIdx.x;           // (b*NH + h)*NC + c
    int c = blk & 63;
    int h = (blk >> 6) & 15;
    int b = blk >> 10;
    float dec = head_decay(h);

    __shared__ float uni[64*65];    // Q (stride 65) phase 1, V half (stride 64) phase 2
    __shared__ float Ks[CL][DK+1];
    __shared__ float Ss[CL][CL+1];
    __shared__ float ascale[CL];
    __shared__ float iscale[CL];

    int tid = threadIdx.x;
    size_t qkbase = ((size_t)(b*SEQ + c*CL))*DM + (size_t)h*DK;
#pragma unroll
    for (int it = 0; it < 2; it++) {
        int s = tid + it*256;       // 0..511 uint4 slots (8 bf16 each)
        int i = s >> 3, c0 = (s & 7)*8;
        uint4 uq = *(const uint4*)&qry[qkbase + (size_t)i*DM + c0];
        uint4 uk = *(const uint4*)&key[qkbase + (size_t)i*DM + c0];
        unpack8(uq, &uni[i*65 + c0]);
        unpack8(uk, &Ks[i][c0]);
    }
    if (tid < CL) {                 // attn_scale via explicit series (closed form cancels at h=15)
        float ssum = 0.f;
        for (int t = 0; t <= tid; t++) ssum += expf(dec * (float)t);
        ascale[tid] = sqrtf(ssum);
    }
    __syncthreads();

    // S = (Q @ K^T) * mask / ascale
    {
        int tx = tid & 15, ty = tid >> 4;
        float acc[4][4] = {};
        for (int d = 0; d < DK; d++) {
            float av[4], bv[4];
#pragma unroll
            for (int i = 0; i < 4; i++) av[i] = uni[(ty*4+i)*65 + d];
#pragma unroll
            for (int j = 0; j < 4; j++) bv[j] = Ks[tx*4+j][d];
#pragma unroll
            for (int i = 0; i < 4; i++)
#pragma unroll
                for (int j = 0; j < 4; j++)
                    acc[i][j] += av[i]*bv[j];
        }
#pragma unroll
        for (int i = 0; i < 4; i++) {
            int ri = ty*4 + i;
            float ra = 1.f / ascale[ri];
#pragma unroll
            for (int j = 0; j < 4; j++) {
                int cj = tx*4 + j;
                float m = (cj <= ri) ? expf(dec*(float)(ri-cj)) * ra : 0.f;
                Ss[ri][cj] = acc[i][j] * m;
            }
        }
    }
    __syncthreads();
    if (tid < CL) {                 // inner_scale = max(|row sum|, 1)
        float rs = 0.f;
        for (int j = 0; j < CL; j++) rs += Ss[tid][j];
        float isc = fmaxf(fabsf(rs), 1.f);
        iscale[tid] = isc;
        iscale_out[(size_t)blk*CL + tid] = isc;
    }

    // phase 2: (S/iscale)@V and K^T@V, V in two 64-col halves overlaying dead Q
    int txv = tid & 15, tyv = tid >> 4;
    int v0 = txv*4, i0 = tyv*4;
    size_t vbase = ((size_t)(b*SEQ + c*CL))*DG + (size_t)h*DV;
    for (int half = 0; half < 2; half++) {
        __syncthreads();            // prior uni readers done; iscale visible
#pragma unroll
        for (int it = 0; it < 2; it++) {
            int s = tid + it*256;
            int i = s >> 3, c0 = (s & 7)*8;
            uint4 uv = *(const uint4*)&valio[vbase + (size_t)i*DG + half*64 + c0];
            unpack8(uv, &uni[i*64 + c0]);
        }
        __syncthreads();
        float acc2[4][4] = {};
        float acc3[4][4] = {};
        for (int j = 0; j < CL; j++) {
            float4 vv = *(const float4*)&uni[j*64 + v0];
            float va[4] = {vv.x, vv.y, vv.z, vv.w};
#pragma unroll
            for (int r = 0; r < 4; r++) {
                float s  = Ss[i0+r][j];
                float kk = Ks[j][i0+r];
#pragma unroll
                for (int q = 0; q < 4; q++) {
                    acc2[r][q] += s*va[q];
                    acc3[r][q] += kk*va[q];
                }
            }
        }
#pragma unroll
        for (int r = 0; r < 4; r++) {
            int i = i0 + r;
            float inv = 1.f / iscale[i];
            uint2 p;
            p.x = pack2(acc2[r][0]*inv, acc2[r][1]*inv);
            p.y = pack2(acc2[r][2]*inv, acc2[r][3]*inv);
            *(uint2*)&valio[vbase + (size_t)i*DG + half*64 + v0] = p;   // own elems only
            float4 kvo = make_float4(acc3[r][0], acc3[r][1], acc3[r][2], acc3[r][3]);
            *(float4*)&kv_out[(size_t)blk*(DK*DV) + (size_t)i*DV + half*64 + v0] = kvo;
        }
    }
}

// ---------------- sequential scan over chunks (in-place KV -> cross_chunk) ----------------
__global__ __launch_bounds__(256) void ret_scan_kernel(float* __restrict__ kv,
        float* __restrict__ cscale_out) {
    int tid = threadIdx.x;
    int col = blockIdx.x*16 + ((tid >> 6) << 2) + (tid & 3);  // 0..4095
    int kp  = (tid >> 2) & 15;
    int v   = col & 127;
    int bh  = col >> 7;
    int h   = bh & 15;
    float dec = head_decay(h);
    float cdecay = expf(dec * (float)CL);
    float state[4] = {0.f, 0.f, 0.f, 0.f};
    float scale = 1.f;
    size_t base0 = (size_t)bh*NC*(DK*DV) + (size_t)(kp*4)*DV + v;
    float cur[4];
#pragma unroll
    for (int kk = 0; kk < 4; kk++) cur[kk] = kv[base0 + (size_t)kk*DV];
    for (int c = 0; c < NC; c++) {
        size_t base = base0 + (size_t)c*(DK*DV);
        float nxt[4];
        if (c+1 < NC) {
            size_t nb = base + (size_t)(DK*DV);
#pragma unroll
            for (int kk = 0; kk < 4; kk++) nxt[kk] = kv[nb + (size_t)kk*DV];
        }
        float inv = 1.f / scale;
#pragma unroll
        for (int kk = 0; kk < 4; kk++) kv[base + (size_t)kk*DV] = cur[kk]*inv;
        if (kp == 0) cscale_out[((size_t)bh*NC + c)*DV + v] = scale;
        float ssum = 0.f;
#pragma unroll
        for (int kk = 0; kk < 4; kk++) {
            state[kk] = state[kk]*cdecay + cur[kk];
            ssum += fabsf(state[kk]);
        }
        ssum += __shfl_xor(ssum, 4);
        ssum += __shfl_xor(ssum, 8);
        ssum += __shfl_xor(ssum, 16);
        ssum += __shfl_xor(ssum, 32);
        scale = fmaxf(ssum, 1.f);
        if (c+1 < NC) {
#pragma unroll
            for (int kk = 0; kk < 4; kk++) cur[kk] = nxt[kk];
        }
    }
}

// ---------------- cross_out + combine + groupnorm + silu(gate), in-place bf16 ----------------
__global__ __launch_bounds__(256) void ret_cross_kernel(
        const unsigned short* __restrict__ qry, const float* __restrict__ cross_chunk,
        unsigned short* __restrict__ valio, const float* __restrict__ iscale,
        const float* __restrict__ cscale, const unsigned short* __restrict__ gatebf,
        const float* __restrict__ gn_g, const float* __restrict__ gn_b) {
    int blk = blockIdx.x;
    int c = blk & 63, h = (blk >> 6) & 15, b = blk >> 10;
    float dec = head_decay(h);
    __shared__ float Qs[CL][DK+1];
    __shared__ float CC[DK][DV];
    __shared__ float asc[CL];
    __shared__ float idec[CL];

    int tid = threadIdx.x;
    size_t qbase = ((size_t)(b*SEQ + c*CL))*DM + (size_t)h*DK;
#pragma unroll
    for (int it = 0; it < 2; it++) {
        int s = tid + it*256;
        int i = s >> 3, c0 = (s & 7)*8;
        uint4 uq = *(const uint4*)&qry[qbase + (size_t)i*DM + c0];
        unpack8(uq, &Qs[i][c0]);
    }
    size_t cbase = (size_t)blk * (DK*DV);
#pragma unroll
    for (int t = 0; t < 32; t++) {
        int idx = tid + t*256;
        CC[idx >> 7][idx & 127] = cross_chunk[cbase + idx];
    }
    if (tid < CL) {
        float ssum = 0.f;
        for (int t = 0; t <= tid; t++) ssum += expf(dec * (float)t);
        asc[tid] = sqrtf(ssum);
    }
    __syncthreads();
    if (tid < CL) idec[tid] = expf(dec*(float)(tid+1)) * asc[CL-1] / asc[tid];
    __syncthreads();

    int txv = tid & 31, tyv = tid >> 5;
    int v0 = txv*4, i0 = tyv*8;
    float acc[8][4] = {};
    for (int k = 0; k < DK; k++) {
        float4 cv = *(const float4*)&CC[k][v0];
        float ca[4] = {cv.x, cv.y, cv.z, cv.w};
#pragma unroll
        for (int r = 0; r < 8; r++) {
            float qv = Qs[i0+r][k];
#pragma unroll
            for (int q = 0; q < 4; q++) acc[r][q] += qv*ca[q];
        }
    }
    float4 csv = *(const float4*)&cscale[(size_t)blk*DV + v0];
    float csa[4] = {csv.x, csv.y, csv.z, csv.w};
    float o[8][4];
    float s1[8], s2[8];
#pragma unroll
    for (int r = 0; r < 8; r++) {
        int i = i0 + r;
        float f2 = idec[i] / iscale[(size_t)blk*CL + i];
        size_t orow = ((size_t)(b*SEQ + c*CL + i))*DG + (size_t)h*DV + v0;
        uint2 iu = *(const uint2*)&valio[orow];
        float ioa[4] = { bf2f((unsigned short)(iu.x & 0xffff)),
                         bf2f((unsigned short)(iu.x >> 16)),
                         bf2f((unsigned short)(iu.y & 0xffff)),
                         bf2f((unsigned short)(iu.y >> 16)) };
        float rs1 = 0.f, rs2 = 0.f;
#pragma unroll
        for (int q = 0; q < 4; q++) {
            float ov = ioa[q]/csa[q] + acc[r][q]*f2;
            o[r][q] = ov;
            rs1 += ov; rs2 += ov*ov;
        }
        s1[r] = rs1; s2[r] = rs2;
    }
    // groupnorm over the head's 128 v's: reduce across 32 txv lanes
#pragma unroll
    for (int r = 0; r < 8; r++) {
#pragma unroll
        for (int m = 1; m <= 16; m <<= 1) {
            s1[r] += __shfl_xor(s1[r], m);
            s2[r] += __shfl_xor(s2[r], m);
        }
    }
#pragma unroll
    for (int r = 0; r < 8; r++) {
        int i = i0 + r;
        float mu = s1[r] * (1.f/DV);
        float var = s2[r] * (1.f/DV) - mu*mu;
        float rstd = rsqrtf(var + 1e-5f);
        size_t orow = ((size_t)(b*SEQ + c*CL + i))*DG + (size_t)h*DV + v0;
        uint2 gu = *(const uint2*)&gatebf[orow];
        float ga[4] = { bf2f((unsigned short)(gu.x & 0xffff)),
                        bf2f((unsigned short)(gu.x >> 16)),
                        bf2f((unsigned short)(gu.y & 0xffff)),
                        bf2f((unsigned short)(gu.y >> 16)) };
        float res[4];
#pragma unroll
        for (int q = 0; q < 4; q++) {
            int col = h*DV + v0 + q;
            float xn = (o[r][q] - mu)*rstd*gn_g[col] + gn_b[col];
            float sg = ga[q] / (1.f + expf(-ga[q]));
            res[q] = xn * sg;
        }
        uint2 p; p.x = pack2(res[0], res[1]); p.y = pack2(res[2], res[3]);
        *(uint2*)&valio[orow] = p;       // in-place: same elems this thread read
    }
}

extern "C" void kernel_launch(void* const* d_in, const int* in_sizes, int n_in,
                              void* d_out, int out_size, void* d_ws, size_t ws_size,
                              hipStream_t stream) {
    (void)in_sizes; (void)n_in; (void)out_size; (void)ws_size;
    const float* x    = (const float*)d_in[0];
    const float* W_q  = (const float*)d_in[2];
    const float* b_q  = (const float*)d_in[3];
    const float* W_k  = (const float*)d_in[4];
    const float* b_k  = (const float*)d_in[5];
    const float* W_v  = (const float*)d_in[6];
    const float* b_v  = (const float*)d_in[7];
    const float* W_g  = (const float*)d_in[8];
    const float* b_g  = (const float*)d_in[9];
    const float* W_o  = (const float*)d_in[10];
    const float* b_o  = (const float*)d_in[11];
    const float* ln_g = (const float*)d_in[12];
    const float* ln_b = (const float*)d_in[13];
    const float* gn_g = (const float*)d_in[14];
    const float* gn_b = (const float*)d_in[15];
    float* out = (float*)d_out;
    float* ws  = (float*)d_ws;

    // workspace layout (floats) — total ~39.2M floats = 157 MB
    float* keyb   = ws;                       //  4,194,304 (bf16 key 8192x1024)
    float* valb   = keyb   + 4194304;         //  8,388,608 (bf16 val->inner_out->acts 8192x2048)
    float* gateb  = valb   + 8388608;         //  8,388,608 (bf16 gate)
    float* kvbuf  = gateb  + 8388608;         // 16,777,216 fp32 KV->cross_chunk
    float* iscale = kvbuf  + 16777216;        //    131,072
    float* cscale = iscale + 131072;          //    262,144
    float* wobuf  = cscale + 262144;          //  1,048,576 (bf16 W_o 1024x2048)

    // bf16 views aliased over kvbuf (dead until ret_inner writes kvbuf)
    unsigned short* xbf  = (unsigned short*)kvbuf;             // 8,388,608 bf16
    unsigned short* Wcat = (unsigned short*)(kvbuf + 4194304); // 6,291,456 bf16 (6144x1024)
    unsigned short* Wo_bf  = (unsigned short*)wobuf;
    unsigned short* key_bf = (unsigned short*)keyb;
    unsigned short* val_bf = (unsigned short*)valb;
    unsigned short* gate_bf= (unsigned short*)gateb;
    unsigned short* qry_bf = (unsigned short*)out;   // d_out doubles as bf16 qry scratch

    ln_cvt_kernel<<<ROWS/4, 256, 0, stream>>>(x, ln_g, ln_b, xbf);
    cvt_bf16_kernel<<<(DM*DM/4 + 255)/256, 256, 0, stream>>>(W_q, Wcat,             DM*DM/4);
    cvt_bf16_kernel<<<(DM*DM/4 + 255)/256, 256, 0, stream>>>(W_k, Wcat + 1048576,   DM*DM/4);
    cvt_bf16_kernel<<<(DG*DM/4 + 255)/256, 256, 0, stream>>>(W_v, Wcat + 2097152,   DG*DM/4);
    cvt_bf16_kernel<<<(DG*DM/4 + 255)/256, 256, 0, stream>>>(W_g, Wcat + 4194304,   DG*DM/4);
    cvt_bf16_kernel<<<(DM*DG/4 + 255)/256, 256, 0, stream>>>(W_o, Wo_bf,            DM*DG/4);

    // fused QKVG: M=8192, Ntot=6144, K=1024 -> 3072 blocks (128^2 tile, 3 blocks/CU)
    gemm_mfma<true><<<(ROWS/128)*(6144/128), 256, 0, stream>>>(
        xbf, Wcat, DM, 6144, b_q, b_k, b_v, b_g,
        qry_bf, key_bf, val_bf, gate_bf);

    ret_inner_kernel<<<BATCH*NH*NC, 256, 0, stream>>>(qry_bf, key_bf, val_bf, kvbuf, iscale);
    ret_scan_kernel<<<256, 256, 0, stream>>>(kvbuf, cscale);
    ret_cross_kernel<<<BATCH*NH*NC, 256, 0, stream>>>(qry_bf, kvbuf, val_bf, iscale, cscale,
                                                      gate_bf, gn_g, gn_b);

    // Wo: M=8192, N=1024, K=2048 -> 512 blocks, fp32 out
    gemm_mfma<false><<<(ROWS/128)*(DM/128), 256, 0, stream>>>(
        val_bf, Wo_bf, DG, DM, b_o, nullptr, nullptr, nullptr,
        out, nullptr, nullptr, nullptr);
}